// Round 3
// baseline (306.619 us; speedup 1.0000x reference)
//
#include <hip/hip_runtime.h>
#include <stdint.h>

typedef _Float16 f16;
typedef _Float16 f16x2 __attribute__((ext_vector_type(2)));
typedef _Float16 f16x4 __attribute__((ext_vector_type(4)));
typedef _Float16 f16x8 __attribute__((ext_vector_type(8)));
typedef float f32x4 __attribute__((ext_vector_type(4)));

typedef __attribute__((address_space(1))) void gvoid;
typedef __attribute__((address_space(3))) void lvoid;

#define NROWS 4096
#define DIMIN 1536
#define DMLP 512
#define FDIM 256
#define NCLS 10000
#define NPAD 10112   // 79 * 128
#define NBMW 320     // bitmap words (>= ceil(NCLS/32)=313)

__device__ __forceinline__ void load_lds16(const void* g, void* l) {
    // async global->LDS, 16B per lane; LDS dest = wave-uniform base + lane*16
    __builtin_amdgcn_global_load_lds((gvoid*)g, (lvoid*)l, 16, 0, 0);
}

// ---------------------------------------------------------------------------
// fp16 GEMM: C[M,N] = A[M,K] @ Bt[N,K]^T (+bias).
// Tile TM x TN per block (256 thr = 4 waves in 2x2), BK=64.
// 2-phase double-buffered pipeline: issue next K-tile's global_load_lds
// BEFORE computing the current tile, ONE __syncthreads per K-step.
// LDS layout per buffer: A then B, row-major [row][64k], XOR swizzle:
// logical 16B-group g of row r lives at slot g ^ (r & 7); staging permutes
// the GLOBAL source address, LDS dest stays linear (global_load_lds rule).
// STATS: fuse BatchNorm column sum/sumsq (atomicAdd) into the epilogue.
// NT: non-temporal C stores (streaming output, keep L2 for operands).
// ---------------------------------------------------------------------------
template<int TM, int TN, bool STATS, bool NT>
__global__ __launch_bounds__(256) void gemm_t(
    const f16* __restrict__ A, const f16* __restrict__ Bt,
    float* __restrict__ C, const float* __restrict__ bias,
    int K, int ldc, int Nstore,
    float* __restrict__ sums, float* __restrict__ sqs)
{
    constexpr int BK = 64;
    constexpr int AM = TM / 32;
    constexpr int AN = TN / 32;
    constexpr int CA = TM * 8;
    constexpr int CB = TN * 8;
    constexpr int RTOT = (CA + CB) / 256;
    constexpr int SPAN = (TM + TN) * BK;
    static_assert(CA % 256 == 0, "A/B staging split must be round-aligned");

    __shared__ f16 smem[2 * SPAN];

    const int tid  = threadIdx.x;
    const int lane = tid & 63;
    const int w    = tid >> 6;
    const int wm   = (w >> 1) * (TM / 2);
    const int wn   = (w & 1) * (TN / 2);
    const int row0 = blockIdx.x * TM;
    const int col0 = blockIdx.y * TN;
    const int quad = lane >> 4;
    const int r16  = lane & 15;

    f32x4 acc[AM][AN] = {};

    const f16* gsrc[RTOT];
    int ldsoff[RTOT];
#pragma unroll
    for (int r = 0; r < RTOT; ++r) {
        int c = tid + r * 256;
        bool isA = (c < CA);
        int cc = isA ? c : c - CA;
        int row = cc >> 3;
        int gs = (cc & 7) ^ (row & 7);
        gsrc[r] = (isA ? A + (size_t)(row0 + row) * K
                       : Bt + (size_t)(col0 + row) * K) + gs * 8;
        ldsoff[r] = (isA ? 0 : TM * BK) + cc * 8;
    }

    const int nt = K / BK;

#pragma unroll
    for (int r = 0; r < RTOT; ++r)
        load_lds16(gsrc[r], smem + ldsoff[r]);
    __syncthreads();

    int buf = 0;
    for (int t = 0; t < nt; ++t) {
        if (t + 1 < nt) {
            const int k0 = (t + 1) * BK;
            const int o = (buf ^ 1) * SPAN;
#pragma unroll
            for (int r = 0; r < RTOT; ++r)
                load_lds16(gsrc[r] + k0, smem + o + ldsoff[r]);
        }
        const f16* As = smem + buf * SPAN;
        const f16* Bs = As + TM * BK;
#pragma unroll
        for (int ks = 0; ks < 2; ++ks) {
            f16x8 af[AM], bq[AN];
#pragma unroll
            for (int mi = 0; mi < AM; ++mi) {
                int row = wm + mi * 16 + r16;
                int slot = (ks * 4 + quad) ^ (r16 & 7);
                af[mi] = *(const f16x8*)&As[row * BK + slot * 8];
            }
#pragma unroll
            for (int ni = 0; ni < AN; ++ni) {
                int row = wn + ni * 16 + r16;
                int slot = (ks * 4 + quad) ^ (r16 & 7);
                bq[ni] = *(const f16x8*)&Bs[row * BK + slot * 8];
            }
#pragma unroll
            for (int mi = 0; mi < AM; ++mi)
#pragma unroll
                for (int ni = 0; ni < AN; ++ni)
                    acc[mi][ni] = __builtin_amdgcn_mfma_f32_16x16x32_f16(
                        af[mi], bq[ni], acc[mi][ni], 0, 0, 0);
        }
        __syncthreads();
        buf ^= 1;
    }

    // C/D layout: col = lane&15, row = quad*4 + reg
#pragma unroll
    for (int ni = 0; ni < AN; ++ni) {
        int col = col0 + wn + ni * 16 + r16;
        float bv = bias ? bias[col] : 0.0f;
        float s = 0.0f, q = 0.0f;
        if (col < Nstore) {
#pragma unroll
            for (int mi = 0; mi < AM; ++mi) {
                int rowb = row0 + wm + mi * 16 + quad * 4;
#pragma unroll
                for (int r = 0; r < 4; ++r) {
                    float v = acc[mi][ni][r] + bv;
                    if constexpr (NT)
                        __builtin_nontemporal_store(v, &C[(size_t)(rowb + r) * ldc + col]);
                    else
                        C[(size_t)(rowb + r) * ldc + col] = v;
                    if constexpr (STATS) { s += v; q += v * v; }
                }
            }
        }
        if constexpr (STATS) {
            s += __shfl_xor(s, 16); s += __shfl_xor(s, 32);
            q += __shfl_xor(q, 16); q += __shfl_xor(q, 32);
            if (quad == 0) {
                atomicAdd(&sums[col], s);
                atomicAdd(&sqs[col], q);
            }
        }
    }
}

// ---------------------------------------------------------------------------
// GEMM2 fused: feat = l2norm(relu(h*bnsc+bnsh) @ W2t^T + b2), fp32+fp16 out.
// TM=64 rows/block, TN=256 = FULL width (so l2norm reduces in-block), BK=64.
// A is reg-staged from fp32 h with the BN transform applied in flight
// (T14 split: issue loads before MFMA, transform+ds_write after), B uses
// global_load_lds. 64 blocks x 256 thr, 8 K-steps, 80.5 KB LDS.
// ---------------------------------------------------------------------------
__global__ __launch_bounds__(256) void gemm2_fused_k(
    const float* __restrict__ h, const float* __restrict__ bnsc,
    const float* __restrict__ bnsh, const f16* __restrict__ W2t,
    const float* __restrict__ b2,
    float* __restrict__ feat, f16* __restrict__ feath)
{
    constexpr int BK = 64, TM = 64, TN = 256;
    constexpr int AM = 2, AN = 8;               // per wave: 32 rows x 128 cols
    constexpr int SPAN = (TM + TN) * BK;        // 20480 f16 = 40 KB / buffer
    constexpr int RB = TN * 8 / 256;            // 8 B-staging rounds

    __shared__ f16 smem[2 * SPAN];
    __shared__ float red[2][TM];

    const int tid  = threadIdx.x;
    const int lane = tid & 63;
    const int w    = tid >> 6;
    const int wm   = (w >> 1) * 32;
    const int wn   = (w & 1) * 128;
    const int row0 = blockIdx.x * TM;
    const int quad = lane >> 4;
    const int r16  = lane & 15;

    // A staging geometry: thread owns chunks cc=2*tid, 2*tid+1
    const int arow = tid >> 2;                  // h row within tile
    const int ak   = (tid & 3) * 16;            // first of 16 k-values
    const int aslot0 = ((tid * 2) & 7) ^ (arow & 7);   // slot of even chunk
    const float* hrow = h + (size_t)(row0 + arow) * DMLP + ak;

    // B staging descriptors
    const f16* gsrcB[RB];
    int ldsoffB[RB];
#pragma unroll
    for (int r = 0; r < RB; ++r) {
        int cc = tid + r * 256;
        int row = cc >> 3;
        int gs = (cc & 7) ^ (row & 7);
        gsrcB[r] = W2t + (size_t)row * DMLP + gs * 8;
        ldsoffB[r] = TM * BK + cc * 8;
    }

    f32x4 acc[AM][AN] = {};
    const int nt = DMLP / BK;                   // 8

    // ---- A load + BN transform + swizzled ds_write for one K-tile ----
    auto stageA = [&](int k0, int bufo) {
        float4 v0 = *(const float4*)&hrow[k0];
        float4 v1 = *(const float4*)&hrow[k0 + 4];
        float4 v2 = *(const float4*)&hrow[k0 + 8];
        float4 v3 = *(const float4*)&hrow[k0 + 12];
        float4 sc0 = *(const float4*)&bnsc[k0 + ak];
        float4 sc1 = *(const float4*)&bnsc[k0 + ak + 4];
        float4 sc2 = *(const float4*)&bnsc[k0 + ak + 8];
        float4 sc3 = *(const float4*)&bnsc[k0 + ak + 12];
        float4 sh0 = *(const float4*)&bnsh[k0 + ak];
        float4 sh1 = *(const float4*)&bnsh[k0 + ak + 4];
        float4 sh2 = *(const float4*)&bnsh[k0 + ak + 8];
        float4 sh3 = *(const float4*)&bnsh[k0 + ak + 12];
        f16x8 c0 = {(f16)fmaxf(v0.x * sc0.x + sh0.x, 0.f),
                    (f16)fmaxf(v0.y * sc0.y + sh0.y, 0.f),
                    (f16)fmaxf(v0.z * sc0.z + sh0.z, 0.f),
                    (f16)fmaxf(v0.w * sc0.w + sh0.w, 0.f),
                    (f16)fmaxf(v1.x * sc1.x + sh1.x, 0.f),
                    (f16)fmaxf(v1.y * sc1.y + sh1.y, 0.f),
                    (f16)fmaxf(v1.z * sc1.z + sh1.z, 0.f),
                    (f16)fmaxf(v1.w * sc1.w + sh1.w, 0.f)};
        f16x8 c1 = {(f16)fmaxf(v2.x * sc2.x + sh2.x, 0.f),
                    (f16)fmaxf(v2.y * sc2.y + sh2.y, 0.f),
                    (f16)fmaxf(v2.z * sc2.z + sh2.z, 0.f),
                    (f16)fmaxf(v2.w * sc2.w + sh2.w, 0.f),
                    (f16)fmaxf(v3.x * sc3.x + sh3.x, 0.f),
                    (f16)fmaxf(v3.y * sc3.y + sh3.y, 0.f),
                    (f16)fmaxf(v3.z * sc3.z + sh3.z, 0.f),
                    (f16)fmaxf(v3.w * sc3.w + sh3.w, 0.f)};
        f16* As = smem + bufo;
        *(f16x8*)&As[arow * BK + aslot0 * 8] = c0;
        *(f16x8*)&As[arow * BK + (aslot0 ^ 1) * 8] = c1;
    };

    // prologue: tile 0 into buffer 0
#pragma unroll
    for (int r = 0; r < RB; ++r)
        load_lds16(gsrcB[r], smem + ldsoffB[r]);
    stageA(0, 0);
    __syncthreads();

    int buf = 0;
    for (int t = 0; t < nt; ++t) {
        float4 n0, n1, n2, n3;
        if (t + 1 < nt) {
            const int k0 = (t + 1) * BK;
            const int o = (buf ^ 1) * SPAN;
#pragma unroll
            for (int r = 0; r < RB; ++r)
                load_lds16(gsrcB[r] + k0, smem + o + ldsoffB[r]);
            // issue A loads now; transform+write after compute
            n0 = *(const float4*)&hrow[k0];
            n1 = *(const float4*)&hrow[k0 + 4];
            n2 = *(const float4*)&hrow[k0 + 8];
            n3 = *(const float4*)&hrow[k0 + 12];
        }
        const f16* As = smem + buf * SPAN;
        const f16* Bs = As + TM * BK;
#pragma unroll
        for (int ks = 0; ks < 2; ++ks) {
            f16x8 af[AM], bq[AN];
#pragma unroll
            for (int mi = 0; mi < AM; ++mi) {
                int row = wm + mi * 16 + r16;
                int slot = (ks * 4 + quad) ^ (r16 & 7);
                af[mi] = *(const f16x8*)&As[row * BK + slot * 8];
            }
#pragma unroll
            for (int ni = 0; ni < AN; ++ni) {
                int row = wn + ni * 16 + r16;
                int slot = (ks * 4 + quad) ^ (r16 & 7);
                bq[ni] = *(const f16x8*)&Bs[row * BK + slot * 8];
            }
#pragma unroll
            for (int mi = 0; mi < AM; ++mi)
#pragma unroll
                for (int ni = 0; ni < AN; ++ni)
                    acc[mi][ni] = __builtin_amdgcn_mfma_f32_16x16x32_f16(
                        af[mi], bq[ni], acc[mi][ni], 0, 0, 0);
        }
        if (t + 1 < nt) {
            const int k0 = (t + 1) * BK;
            const int o = (buf ^ 1) * SPAN;
            float4 sc0 = *(const float4*)&bnsc[k0 + ak];
            float4 sc1 = *(const float4*)&bnsc[k0 + ak + 4];
            float4 sc2 = *(const float4*)&bnsc[k0 + ak + 8];
            float4 sc3 = *(const float4*)&bnsc[k0 + ak + 12];
            float4 sh0 = *(const float4*)&bnsh[k0 + ak];
            float4 sh1 = *(const float4*)&bnsh[k0 + ak + 4];
            float4 sh2 = *(const float4*)&bnsh[k0 + ak + 8];
            float4 sh3 = *(const float4*)&bnsh[k0 + ak + 12];
            f16x8 c0 = {(f16)fmaxf(n0.x * sc0.x + sh0.x, 0.f),
                        (f16)fmaxf(n0.y * sc0.y + sh0.y, 0.f),
                        (f16)fmaxf(n0.z * sc0.z + sh0.z, 0.f),
                        (f16)fmaxf(n0.w * sc0.w + sh0.w, 0.f),
                        (f16)fmaxf(n1.x * sc1.x + sh1.x, 0.f),
                        (f16)fmaxf(n1.y * sc1.y + sh1.y, 0.f),
                        (f16)fmaxf(n1.z * sc1.z + sh1.z, 0.f),
                        (f16)fmaxf(n1.w * sc1.w + sh1.w, 0.f)};
            f16x8 c1 = {(f16)fmaxf(n2.x * sc2.x + sh2.x, 0.f),
                        (f16)fmaxf(n2.y * sc2.y + sh2.y, 0.f),
                        (f16)fmaxf(n2.z * sc2.z + sh2.z, 0.f),
                        (f16)fmaxf(n2.w * sc2.w + sh2.w, 0.f),
                        (f16)fmaxf(n3.x * sc3.x + sh3.x, 0.f),
                        (f16)fmaxf(n3.y * sc3.y + sh3.y, 0.f),
                        (f16)fmaxf(n3.z * sc3.z + sh3.z, 0.f),
                        (f16)fmaxf(n3.w * sc3.w + sh3.w, 0.f)};
            f16* Asn = smem + o;
            *(f16x8*)&Asn[arow * BK + aslot0 * 8] = c0;
            *(f16x8*)&Asn[arow * BK + (aslot0 ^ 1) * 8] = c1;
        }
        __syncthreads();
        buf ^= 1;
    }

    // epilogue: bias, row ssq, cross-wave combine, normalize, store both
    float ssq[AM][4] = {};
#pragma unroll
    for (int ni = 0; ni < AN; ++ni) {
        int col = wn + ni * 16 + r16;
        float bv = b2[col];
#pragma unroll
        for (int mi = 0; mi < AM; ++mi)
#pragma unroll
            for (int r = 0; r < 4; ++r) {
                float v = acc[mi][ni][r] + bv;
                acc[mi][ni][r] = v;
                ssq[mi][r] += v * v;
            }
    }
#pragma unroll
    for (int mi = 0; mi < AM; ++mi)
#pragma unroll
        for (int r = 0; r < 4; ++r) {
            float s = ssq[mi][r];
            s += __shfl_xor(s, 1); s += __shfl_xor(s, 2);
            s += __shfl_xor(s, 4); s += __shfl_xor(s, 8);
            ssq[mi][r] = s;
        }
    if (r16 == 0) {
#pragma unroll
        for (int mi = 0; mi < AM; ++mi)
#pragma unroll
            for (int r = 0; r < 4; ++r)
                red[w & 1][wm + mi * 16 + quad * 4 + r] = ssq[mi][r];
    }
    __syncthreads();
    float inv[AM][4];
#pragma unroll
    for (int mi = 0; mi < AM; ++mi)
#pragma unroll
        for (int r = 0; r < 4; ++r) {
            int rl = wm + mi * 16 + quad * 4 + r;
            float s = red[0][rl] + red[1][rl];
            inv[mi][r] = 1.0f / fmaxf(sqrtf(s), 1e-12f);
        }
#pragma unroll
    for (int ni = 0; ni < AN; ++ni) {
        int col = wn + ni * 16 + r16;
#pragma unroll
        for (int mi = 0; mi < AM; ++mi)
#pragma unroll
            for (int r = 0; r < 4; ++r) {
                int row = row0 + wm + mi * 16 + quad * 4 + r;
                float o = acc[mi][ni][r] * inv[mi][r];
                feat[(size_t)row * FDIM + col] = o;
                feath[(size_t)row * FDIM + col] = (f16)o;
            }
    }
}

// ---------------------------------------------------------------------------
// single-block prep: zero BN stats + build touched-class bitmap in LDS
__global__ void prep_k(const int* __restrict__ label, float* __restrict__ stats,
                       unsigned int* __restrict__ bm) {
    __shared__ unsigned int lbm[NBMW];
    int t = threadIdx.x;
    for (int i = t; i < NBMW; i += 256) lbm[i] = 0u;
    for (int i = t; i < 2 * DMLP; i += 256) stats[i] = 0.0f;
    __syncthreads();
    for (int i = t; i < NROWS; i += 256) {
        int y = label[i];
        atomicOr(&lbm[y >> 5], 1u << (y & 31));
    }
    __syncthreads();
    for (int i = t; i < NBMW; i += 256) bm[i] = lbm[i];
}

__global__ void f32_to_f16_k(const float* __restrict__ in, f16* __restrict__ out, int n4) {
    int i = blockIdx.x * 256 + threadIdx.x;
    if (i >= n4) return;
    float4 v = *(const float4*)&in[(size_t)i * 4];
    f16x4 o = {(f16)v.x, (f16)v.y, (f16)v.z, (f16)v.w};
    *(f16x4*)&out[(size_t)i * 4] = o;
}

// tiled transpose: in [R,C] fp32 -> out [C,R] fp16; 32x32 tiles, 256 thr
__global__ void transpose_f16_tile_k(const float* __restrict__ in, f16* __restrict__ out,
                                     int R, int C) {
    __shared__ float t[32][33];
    int tx = threadIdx.x & 31, ty = threadIdx.x >> 5;   // 32x8
    int c0 = blockIdx.x * 32, r0 = blockIdx.y * 32;
#pragma unroll
    for (int k = 0; k < 4; ++k)
        t[ty + k * 8][tx] = in[(size_t)(r0 + ty + k * 8) * C + c0 + tx];
    __syncthreads();
#pragma unroll
    for (int k = 0; k < 4; ++k)
        out[(size_t)(c0 + ty + k * 8) * R + r0 + tx] = (f16)t[tx][ty + k * 8];
}

// fold BN stats into per-column scale/shift (512 threads total)
__global__ void bn_finish_k(const float* __restrict__ sums, const float* __restrict__ sqs,
                            const float* __restrict__ gamma, const float* __restrict__ beta,
                            float* __restrict__ scale, float* __restrict__ shift) {
    int c = blockIdx.x * 256 + threadIdx.x;
    if (c >= DMLP) return;
    const float inv_n = 1.0f / 4096.0f;
    float mu = sums[c] * inv_n;
    float var = fmaxf(sqs[c] * inv_n - mu * mu, 0.0f);
    float a = rsqrtf(var + 1e-5f) * gamma[c];
    scale[c] = a;
    shift[c] = beta[c] - mu * a;
}

// per-label sequential momentum chain + f16 memory-bank materialization.
// One wave per padded row; rows >= NCLS -> zeros; untouched rows (bitmap
// gate) skip the 64-iteration label scan entirely.
__global__ void chain_k(const int* __restrict__ label, const float* __restrict__ feat,
                        const float* __restrict__ mp, const unsigned int* __restrict__ bm,
                        f16* __restrict__ memh) {
    int y = (blockIdx.x * 256 + threadIdx.x) >> 6;
    int lane = threadIdx.x & 63;
    float4 m = {0.f, 0.f, 0.f, 0.f};
    if (y < NCLS) {
        m = *(const float4*)&mp[(size_t)y * FDIM + lane * 4];
        if ((bm[y >> 5] >> (y & 31)) & 1u) {
            for (int g = 0; g < 64; ++g) {
                int lab = label[g * 64 + lane];
                unsigned long long mask = __ballot(lab == y);
                while (mask) {
                    int b = __builtin_ctzll(mask);
                    mask &= mask - 1;
                    int i = g * 64 + b;
                    float4 x = *(const float4*)&feat[(size_t)i * FDIM + lane * 4];
                    m.x = 0.9f * m.x + 0.1f * x.x;
                    m.y = 0.9f * m.y + 0.1f * x.y;
                    m.z = 0.9f * m.z + 0.1f * x.z;
                    m.w = 0.9f * m.w + 0.1f * x.w;
                    float s = m.x * m.x + m.y * m.y + m.z * m.z + m.w * m.w;
#pragma unroll
                    for (int off = 32; off > 0; off >>= 1) s += __shfl_xor(s, off);
                    float inv = 1.0f / fmaxf(sqrtf(s), 1e-12f);
                    m.x *= inv; m.y *= inv; m.z *= inv; m.w *= inv;
                }
            }
        }
    }
    f16x4 o = {(f16)m.x, (f16)m.y, (f16)m.z, (f16)m.w};
    *(f16x4*)&memh[(size_t)y * FDIM + lane * 4] = o;
}

// ---------------------------------------------------------------------------
extern "C" void kernel_launch(void* const* d_in, const int* in_sizes, int n_in,
                              void* d_out, int out_size, void* d_ws, size_t ws_size,
                              hipStream_t stream) {
    const float* feat_in = (const float*)d_in[0];
    const int*   label   = (const int*)d_in[1];
    const float* W1      = (const float*)d_in[2];
    const float* b1      = (const float*)d_in[3];
    const float* gamma   = (const float*)d_in[4];
    const float* beta    = (const float*)d_in[5];
    const float* W2      = (const float*)d_in[6];
    const float* b2      = (const float*)d_in[7];
    const float* mp      = (const float*)d_in[8];
    float* out = (float*)d_out;

    char* w = (char*)d_ws;
    f16* A1h   = (f16*)w;   w += (size_t)NROWS * DIMIN * 2;   // 12.6 MB
    f16* W1t   = (f16*)w;   w += (size_t)DMLP * DIMIN * 2;    // 1.6 MB
    f16* W2t   = (f16*)w;   w += (size_t)FDIM * DMLP * 2;     // 0.26 MB
    float* h   = (float*)w; w += (size_t)NROWS * DMLP * 4;    // 8.4 MB
    float* feat= (float*)w; w += (size_t)NROWS * FDIM * 4;    // 4.2 MB
    f16* feath = (f16*)w;   w += (size_t)NROWS * FDIM * 2;    // 2.1 MB
    f16* memh  = (f16*)w;   w += (size_t)NPAD * FDIM * 2;     // 5.2 MB
    float* sums= (float*)w; w += DMLP * 4;                    // stats (contig)
    float* sqs = (float*)w; w += DMLP * 4;
    unsigned int* bm = (unsigned int*)w; w += NBMW * 4;       // touched bitmap
    float* bnsc= (float*)w; w += DMLP * 4;
    float* bnsh= (float*)w; w += DMLP * 4;

    // stage 0: prep (stats zero + bitmap) + conversions
    prep_k<<<1, 256, 0, stream>>>(label, sums, bm);
    f32_to_f16_k<<<(NROWS * DIMIN / 4) / 256, 256, 0, stream>>>(feat_in, A1h, NROWS * DIMIN / 4);
    {
        dim3 g1(DMLP / 32, DIMIN / 32);       // W1 [1536,512] -> W1t [512,1536]
        transpose_f16_tile_k<<<g1, 256, 0, stream>>>(W1, W1t, DIMIN, DMLP);
        dim3 g2(FDIM / 32, DMLP / 32);        // W2 [512,256] -> W2t [256,512]
        transpose_f16_tile_k<<<g2, 256, 0, stream>>>(W2, W2t, DMLP, FDIM);
    }

    // GEMM1: h = feat_in @ W1 + b1, BN stats fused (128x64 tiles -> 256 blocks)
    {
        dim3 g(NROWS / 128, DMLP / 64);
        gemm_t<128, 64, true, false><<<g, 256, 0, stream>>>(
            A1h, W1t, h, b1, DIMIN, DMLP, DMLP, sums, sqs);
    }

    // BN finish (scale/shift)
    bn_finish_k<<<2, 256, 0, stream>>>(sums, sqs, gamma, beta, bnsc, bnsh);

    // fused BN-apply + GEMM2 + l2norm -> feat fp32 + feath fp16
    gemm2_fused_k<<<NROWS / 64, 256, 0, stream>>>(h, bnsc, bnsh, W2t, b2, feat, feath);

    // memory bank: per-label chains (bitmap-gated) + f16 materialization
    chain_k<<<NPAD / 4, 256, 0, stream>>>(label, feat, mp, bm, memh);

    // GEMM3: sim = feat @ mem^T   [4096, 10000]  (128x128 tiles -> 2528 blocks,
    // non-temporal C stores: don't let the 164 MB stream evict memh/feath)
    {
        dim3 g(NROWS / 128, NPAD / 128);
        gemm_t<128, 128, false, true><<<g, 256, 0, stream>>>(
            feath, memh, out, nullptr, FDIM, NCLS, NCLS, nullptr, nullptr);
    }
}

// Round 5
// 305.062 us; speedup vs baseline: 1.0051x; 1.0051x over previous
//
#include <hip/hip_runtime.h>
#include <stdint.h>

typedef _Float16 f16;
typedef _Float16 f16x4 __attribute__((ext_vector_type(4)));
typedef _Float16 f16x8 __attribute__((ext_vector_type(8)));
typedef float f32x4 __attribute__((ext_vector_type(4)));

typedef __attribute__((address_space(1))) void gvoid;
typedef __attribute__((address_space(3))) void lvoid;

#define NROWS 4096
#define DIMIN 1536
#define DMLP 512
#define FDIM 256
#define NCLS 10000
#define NPAD 10112   // 79 * 128
#define NBMW 320     // bitmap words (>= ceil(NCLS/32)=313)

__device__ __forceinline__ void load_lds16(const void* g, void* l) {
    // async global->LDS, 16B per lane; LDS dest = wave-uniform base + lane*16
    __builtin_amdgcn_global_load_lds((gvoid*)g, (lvoid*)l, 16, 0, 0);
}

// ---------------------------------------------------------------------------
// fp16 GEMM: C[M,N] = A[M,K] @ Bt[N,K]^T (+bias).  (used for GEMM3)
// Tile TM x TN per block (256 thr = 4 waves in 2x2), BK=64.
// 2-phase double-buffered pipeline: issue next K-tile's global_load_lds
// BEFORE computing the current tile, ONE __syncthreads per K-step.
// LDS per buffer: A then B, row-major [row][64k], XOR swizzle: 16B-group g
// of row r lives at slot g ^ (r & 7); staging permutes the GLOBAL source
// address, LDS dest stays linear (global_load_lds rule).
// NT: non-temporal C stores (streaming output, keep L2 for operands).
// ---------------------------------------------------------------------------
template<int TM, int TN, bool STATS, bool NT>
__global__ __launch_bounds__(256) void gemm_t(
    const f16* __restrict__ A, const f16* __restrict__ Bt,
    float* __restrict__ C, const float* __restrict__ bias,
    int K, int ldc, int Nstore,
    float* __restrict__ sums, float* __restrict__ sqs)
{
    constexpr int BK = 64;
    constexpr int AM = TM / 32;
    constexpr int AN = TN / 32;
    constexpr int CA = TM * 8;
    constexpr int CB = TN * 8;
    constexpr int RTOT = (CA + CB) / 256;
    constexpr int SPAN = (TM + TN) * BK;
    static_assert(CA % 256 == 0, "A/B staging split must be round-aligned");

    __shared__ f16 smem[2 * SPAN];

    const int tid  = threadIdx.x;
    const int lane = tid & 63;
    const int w    = tid >> 6;
    const int wm   = (w >> 1) * (TM / 2);
    const int wn   = (w & 1) * (TN / 2);
    const int row0 = blockIdx.x * TM;
    const int col0 = blockIdx.y * TN;
    const int quad = lane >> 4;
    const int r16  = lane & 15;

    f32x4 acc[AM][AN] = {};

    const f16* gsrc[RTOT];
    int ldsoff[RTOT];
#pragma unroll
    for (int r = 0; r < RTOT; ++r) {
        int c = tid + r * 256;
        bool isA = (c < CA);
        int cc = isA ? c : c - CA;
        int row = cc >> 3;
        int gs = (cc & 7) ^ (row & 7);
        gsrc[r] = (isA ? A + (size_t)(row0 + row) * K
                       : Bt + (size_t)(col0 + row) * K) + gs * 8;
        ldsoff[r] = (isA ? 0 : TM * BK) + cc * 8;
    }

    const int nt = K / BK;

#pragma unroll
    for (int r = 0; r < RTOT; ++r)
        load_lds16(gsrc[r], smem + ldsoff[r]);
    __syncthreads();

    int buf = 0;
    for (int t = 0; t < nt; ++t) {
        if (t + 1 < nt) {
            const int k0 = (t + 1) * BK;
            const int o = (buf ^ 1) * SPAN;
#pragma unroll
            for (int r = 0; r < RTOT; ++r)
                load_lds16(gsrc[r] + k0, smem + o + ldsoff[r]);
        }
        const f16* As = smem + buf * SPAN;
        const f16* Bs = As + TM * BK;
#pragma unroll
        for (int ks = 0; ks < 2; ++ks) {
            f16x8 af[AM], bq[AN];
#pragma unroll
            for (int mi = 0; mi < AM; ++mi) {
                int row = wm + mi * 16 + r16;
                int slot = (ks * 4 + quad) ^ (r16 & 7);
                af[mi] = *(const f16x8*)&As[row * BK + slot * 8];
            }
#pragma unroll
            for (int ni = 0; ni < AN; ++ni) {
                int row = wn + ni * 16 + r16;
                int slot = (ks * 4 + quad) ^ (r16 & 7);
                bq[ni] = *(const f16x8*)&Bs[row * BK + slot * 8];
            }
#pragma unroll
            for (int mi = 0; mi < AM; ++mi)
#pragma unroll
                for (int ni = 0; ni < AN; ++ni)
                    acc[mi][ni] = __builtin_amdgcn_mfma_f32_16x16x32_f16(
                        af[mi], bq[ni], acc[mi][ni], 0, 0, 0);
        }
        __syncthreads();
        buf ^= 1;
    }

    // C/D layout: col = lane&15, row = quad*4 + reg
#pragma unroll
    for (int ni = 0; ni < AN; ++ni) {
        int col = col0 + wn + ni * 16 + r16;
        float bv = bias ? bias[col] : 0.0f;
        float s = 0.0f, q = 0.0f;
        if (col < Nstore) {
#pragma unroll
            for (int mi = 0; mi < AM; ++mi) {
                int rowb = row0 + wm + mi * 16 + quad * 4;
#pragma unroll
                for (int r = 0; r < 4; ++r) {
                    float v = acc[mi][ni][r] + bv;
                    if constexpr (NT)
                        __builtin_nontemporal_store(v, &C[(size_t)(rowb + r) * ldc + col]);
                    else
                        C[(size_t)(rowb + r) * ldc + col] = v;
                    if constexpr (STATS) { s += v; q += v * v; }
                }
            }
        }
        if constexpr (STATS) {
            s += __shfl_xor(s, 16); s += __shfl_xor(s, 32);
            q += __shfl_xor(q, 16); q += __shfl_xor(q, 32);
            if (quad == 0) {
                atomicAdd(&sums[col], s);
                atomicAdd(&sqs[col], q);
            }
        }
    }
}

// ---------------------------------------------------------------------------
// fp32-A GEMM with fused elementwise pre-transform in the A-staging.
// C[M,N] = xform(Af)[M,K] @ Bt[N,K]^T + bias.
//   BNA=false: xform = RNE f16 cast                (GEMM1: conv fused)
//   BNA=true : xform = (f16)relu(a*sc[k]+sh[k])    (GEMM2: BN-apply fused)
// TM=64 fixed, TN in {64,128}; grid is 1D 256 blocks, XCD-clustered:
// the 4 blocks sharing an A row-panel land on the SAME XCD (dispatch
// round-robins linear id % 8 over XCDs), so fp32 A re-reads hit that
// XCD's L2 instead of L3.  A is reg-staged (loads issued before MFMA,
// convert + swizzled ds_write after — T14 split); B via global_load_lds.
// ---------------------------------------------------------------------------
template<int TN, bool BNA, bool STATS>
__global__ __launch_bounds__(256) void gemm_f32a_t(
    const float* __restrict__ Af, const f16* __restrict__ Bt,
    const float* __restrict__ sc, const float* __restrict__ sh,
    float* __restrict__ C, const float* __restrict__ bias,
    int K, int ldc,
    float* __restrict__ sums, float* __restrict__ sqs)
{
    constexpr int TM = 64, BK = 64;
    constexpr int AM = TM / 32;          // 2
    constexpr int AN = TN / 32;          // 4 or 2
    constexpr int RA = TM * 8 / 256;     // 2 A chunks per thread
    constexpr int RB = TN * 8 / 256;     // 4 or 2 B staging rounds
    constexpr int SPAN = (TM + TN) * BK;

    __shared__ f16 smem[2 * SPAN];

    const int tid  = threadIdx.x;
    const int lane = tid & 63;
    const int w    = tid >> 6;
    const int wm   = (w >> 1) * (TM / 2);
    const int wn   = (w & 1) * (TN / 2);
    // XCD-clustered decompose of lin -> (bx in [0,64), by in [0,4))
    const int lin  = blockIdx.x;
    const int bx   = (lin & 7) * 8 + (lin >> 5);
    const int by   = (lin >> 3) & 3;
    const int row0 = bx * TM;
    const int col0 = by * TN;
    const int quad = lane >> 4;
    const int r16  = lane & 15;

    f32x4 acc[AM][AN] = {};

    // A chunk descriptors (reg-staged, swizzle applied on the LDS WRITE)
    const float* asrc[RA];
    int ag8[RA], adst[RA];
#pragma unroll
    for (int r = 0; r < RA; ++r) {
        int cc = tid + r * 256;
        int row = cc >> 3, g = cc & 7;
        asrc[r] = Af + (size_t)(row0 + row) * K + g * 8;
        ag8[r]  = g * 8;
        adst[r] = row * BK + (g ^ (row & 7)) * 8;
    }
    // B staging descriptors (global_load_lds, swizzle on the SOURCE)
    const f16* gsrcB[RB];
    int ldsoffB[RB];
#pragma unroll
    for (int r = 0; r < RB; ++r) {
        int cc = tid + r * 256;
        int row = cc >> 3, g = cc & 7;
        gsrcB[r] = Bt + (size_t)(col0 + row) * K + (g ^ (row & 7)) * 8;
        ldsoffB[r] = TM * BK + cc * 8;
    }

    auto xform = [&](float4 a, float4 b, int k) -> f16x8 {
        if constexpr (BNA) {
            float4 s0 = *(const float4*)&sc[k], s1 = *(const float4*)&sc[k + 4];
            float4 h0 = *(const float4*)&sh[k], h1 = *(const float4*)&sh[k + 4];
            return f16x8{(f16)fmaxf(a.x * s0.x + h0.x, 0.f),
                         (f16)fmaxf(a.y * s0.y + h0.y, 0.f),
                         (f16)fmaxf(a.z * s0.z + h0.z, 0.f),
                         (f16)fmaxf(a.w * s0.w + h0.w, 0.f),
                         (f16)fmaxf(b.x * s1.x + h1.x, 0.f),
                         (f16)fmaxf(b.y * s1.y + h1.y, 0.f),
                         (f16)fmaxf(b.z * s1.z + h1.z, 0.f),
                         (f16)fmaxf(b.w * s1.w + h1.w, 0.f)};
        } else {
            return f16x8{(f16)a.x, (f16)a.y, (f16)a.z, (f16)a.w,
                         (f16)b.x, (f16)b.y, (f16)b.z, (f16)b.w};
        }
    };

    const int nt = K / BK;

    // prologue: tile 0 into buffer 0
#pragma unroll
    for (int r = 0; r < RB; ++r)
        load_lds16(gsrcB[r], smem + ldsoffB[r]);
#pragma unroll
    for (int r = 0; r < RA; ++r) {
        float4 a = *(const float4*)(asrc[r]);
        float4 b = *(const float4*)(asrc[r] + 4);
        *(f16x8*)&smem[adst[r]] = xform(a, b, ag8[r]);
    }
    __syncthreads();

    int buf = 0;
    for (int t = 0; t < nt; ++t) {
        float4 na[RA], nb[RA];
        if (t + 1 < nt) {
            const int k0n = (t + 1) * BK;
            const int o = (buf ^ 1) * SPAN;
#pragma unroll
            for (int r = 0; r < RB; ++r)
                load_lds16(gsrcB[r] + k0n, smem + o + ldsoffB[r]);
#pragma unroll
            for (int r = 0; r < RA; ++r) {          // issue A loads early
                na[r] = *(const float4*)(asrc[r] + k0n);
                nb[r] = *(const float4*)(asrc[r] + k0n + 4);
            }
        }
        const f16* As = smem + buf * SPAN;
        const f16* Bs = As + TM * BK;
#pragma unroll
        for (int ks = 0; ks < 2; ++ks) {
            f16x8 af[AM], bq[AN];
#pragma unroll
            for (int mi = 0; mi < AM; ++mi) {
                int row = wm + mi * 16 + r16;
                int slot = (ks * 4 + quad) ^ (r16 & 7);
                af[mi] = *(const f16x8*)&As[row * BK + slot * 8];
            }
#pragma unroll
            for (int ni = 0; ni < AN; ++ni) {
                int row = wn + ni * 16 + r16;
                int slot = (ks * 4 + quad) ^ (r16 & 7);
                bq[ni] = *(const f16x8*)&Bs[row * BK + slot * 8];
            }
#pragma unroll
            for (int mi = 0; mi < AM; ++mi)
#pragma unroll
                for (int ni = 0; ni < AN; ++ni)
                    acc[mi][ni] = __builtin_amdgcn_mfma_f32_16x16x32_f16(
                        af[mi], bq[ni], acc[mi][ni], 0, 0, 0);
        }
        if (t + 1 < nt) {                            // convert + write late
            const int k0n = (t + 1) * BK;
            f16* Ad = smem + (buf ^ 1) * SPAN;
#pragma unroll
            for (int r = 0; r < RA; ++r)
                *(f16x8*)&Ad[adst[r]] = xform(na[r], nb[r], k0n + ag8[r]);
        }
        __syncthreads();
        buf ^= 1;
    }

    // epilogue (exact-fit grids: no bound check; bias always present)
#pragma unroll
    for (int ni = 0; ni < AN; ++ni) {
        int col = col0 + wn + ni * 16 + r16;
        float bv = bias[col];
        float s = 0.0f, q = 0.0f;
#pragma unroll
        for (int mi = 0; mi < AM; ++mi) {
            int rowb = row0 + wm + mi * 16 + quad * 4;
#pragma unroll
            for (int r = 0; r < 4; ++r) {
                float v = acc[mi][ni][r] + bv;
                C[(size_t)(rowb + r) * ldc + col] = v;
                if constexpr (STATS) { s += v; q += v * v; }
            }
        }
        if constexpr (STATS) {
            s += __shfl_xor(s, 16); s += __shfl_xor(s, 32);
            q += __shfl_xor(q, 16); q += __shfl_xor(q, 32);
            if (quad == 0) {
                atomicAdd(&sums[col], s);
                atomicAdd(&sqs[col], q);
            }
        }
    }
}

// ---------------------------------------------------------------------------
// single-block prep: zero BN stats + build touched-class bitmap in LDS
__global__ void prep_k(const int* __restrict__ label, float* __restrict__ stats,
                       unsigned int* __restrict__ bm) {
    __shared__ unsigned int lbm[NBMW];
    int t = threadIdx.x;
    for (int i = t; i < NBMW; i += 256) lbm[i] = 0u;
    for (int i = t; i < 2 * DMLP; i += 256) stats[i] = 0.0f;
    __syncthreads();
    for (int i = t; i < NROWS; i += 256) {
        int y = label[i];
        atomicOr(&lbm[y >> 5], 1u << (y & 31));
    }
    __syncthreads();
    for (int i = t; i < NBMW; i += 256) bm[i] = lbm[i];
}

// tiled transpose: in [R,C] fp32 -> out [C,R] fp16; 32x32 tiles, 256 thr
__global__ void transpose_f16_tile_k(const float* __restrict__ in, f16* __restrict__ out,
                                     int R, int C) {
    __shared__ float t[32][33];
    int tx = threadIdx.x & 31, ty = threadIdx.x >> 5;   // 32x8
    int c0 = blockIdx.x * 32, r0 = blockIdx.y * 32;
#pragma unroll
    for (int k = 0; k < 4; ++k)
        t[ty + k * 8][tx] = in[(size_t)(r0 + ty + k * 8) * C + c0 + tx];
    __syncthreads();
#pragma unroll
    for (int k = 0; k < 4; ++k)
        out[(size_t)(c0 + ty + k * 8) * R + r0 + tx] = (f16)t[tx][ty + k * 8];
}

// fold BN stats into per-column scale/shift (512 threads total)
__global__ void bn_finish_k(const float* __restrict__ sums, const float* __restrict__ sqs,
                            const float* __restrict__ gamma, const float* __restrict__ beta,
                            float* __restrict__ scale, float* __restrict__ shift) {
    int c = blockIdx.x * 256 + threadIdx.x;
    if (c >= DMLP) return;
    const float inv_n = 1.0f / 4096.0f;
    float mu = sums[c] * inv_n;
    float var = fmaxf(sqs[c] * inv_n - mu * mu, 0.0f);
    float a = rsqrtf(var + 1e-5f) * gamma[c];
    scale[c] = a;
    shift[c] = beta[c] - mu * a;
}

// row-wise L2 normalize out2[4096,256] -> feat fp32 + fp16; one wave/row
__global__ void l2norm_k(const float* __restrict__ X, float* __restrict__ Y, f16* __restrict__ Yh) {
    int wv = (blockIdx.x * 256 + threadIdx.x) >> 6;
    int lane = threadIdx.x & 63;
    float4 v = *(const float4*)&X[(size_t)wv * FDIM + lane * 4];
    float s = v.x * v.x + v.y * v.y + v.z * v.z + v.w * v.w;
#pragma unroll
    for (int off = 32; off > 0; off >>= 1) s += __shfl_xor(s, off);
    float inv = 1.0f / fmaxf(sqrtf(s), 1e-12f);
    float4 o = {v.x * inv, v.y * inv, v.z * inv, v.w * inv};
    *(float4*)&Y[(size_t)wv * FDIM + lane * 4] = o;
    f16x4 oh = {(f16)o.x, (f16)o.y, (f16)o.z, (f16)o.w};
    *(f16x4*)&Yh[(size_t)wv * FDIM + lane * 4] = oh;
}

// per-label sequential momentum chain + f16 memory-bank materialization.
// One wave per padded row; rows >= NCLS -> zeros; untouched rows (bitmap
// gate) skip the 64-iteration label scan entirely.
__global__ void chain_k(const int* __restrict__ label, const float* __restrict__ feat,
                        const float* __restrict__ mp, const unsigned int* __restrict__ bm,
                        f16* __restrict__ memh) {
    int y = (blockIdx.x * 256 + threadIdx.x) >> 6;
    int lane = threadIdx.x & 63;
    float4 m = {0.f, 0.f, 0.f, 0.f};
    if (y < NCLS) {
        m = *(const float4*)&mp[(size_t)y * FDIM + lane * 4];
        if ((bm[y >> 5] >> (y & 31)) & 1u) {
            for (int g = 0; g < 64; ++g) {
                int lab = label[g * 64 + lane];
                unsigned long long mask = __ballot(lab == y);
                while (mask) {
                    int b = __builtin_ctzll(mask);
                    mask &= mask - 1;
                    int i = g * 64 + b;
                    float4 x = *(const float4*)&feat[(size_t)i * FDIM + lane * 4];
                    m.x = 0.9f * m.x + 0.1f * x.x;
                    m.y = 0.9f * m.y + 0.1f * x.y;
                    m.z = 0.9f * m.z + 0.1f * x.z;
                    m.w = 0.9f * m.w + 0.1f * x.w;
                    float s = m.x * m.x + m.y * m.y + m.z * m.z + m.w * m.w;
#pragma unroll
                    for (int off = 32; off > 0; off >>= 1) s += __shfl_xor(s, off);
                    float inv = 1.0f / fmaxf(sqrtf(s), 1e-12f);
                    m.x *= inv; m.y *= inv; m.z *= inv; m.w *= inv;
                }
            }
        }
    }
    f16x4 o = {(f16)m.x, (f16)m.y, (f16)m.z, (f16)m.w};
    *(f16x4*)&memh[(size_t)y * FDIM + lane * 4] = o;
}

// ---------------------------------------------------------------------------
extern "C" void kernel_launch(void* const* d_in, const int* in_sizes, int n_in,
                              void* d_out, int out_size, void* d_ws, size_t ws_size,
                              hipStream_t stream) {
    const float* feat_in = (const float*)d_in[0];
    const int*   label   = (const int*)d_in[1];
    const float* W1      = (const float*)d_in[2];
    const float* b1      = (const float*)d_in[3];
    const float* gamma   = (const float*)d_in[4];
    const float* beta    = (const float*)d_in[5];
    const float* W2      = (const float*)d_in[6];
    const float* b2      = (const float*)d_in[7];
    const float* mp      = (const float*)d_in[8];
    float* out = (float*)d_out;

    char* w = (char*)d_ws;
    f16* W1t   = (f16*)w;   w += (size_t)DMLP * DIMIN * 2;    // 1.6 MB
    f16* W2t   = (f16*)w;   w += (size_t)FDIM * DMLP * 2;     // 0.26 MB
    float* h   = (float*)w; w += (size_t)NROWS * DMLP * 4;    // 8.4 MB
    float* out2= (float*)w; w += (size_t)NROWS * FDIM * 4;    // 4.2 MB
    float* feat= (float*)w; w += (size_t)NROWS * FDIM * 4;    // 4.2 MB
    f16* feath = (f16*)w;   w += (size_t)NROWS * FDIM * 2;    // 2.1 MB
    f16* memh  = (f16*)w;   w += (size_t)NPAD * FDIM * 2;     // 5.2 MB
    float* sums= (float*)w; w += DMLP * 4;                    // stats (contig)
    float* sqs = (float*)w; w += DMLP * 4;
    unsigned int* bm = (unsigned int*)w; w += NBMW * 4;       // touched bitmap
    float* bnsc= (float*)w; w += DMLP * 4;
    float* bnsh= (float*)w; w += DMLP * 4;

    // stage 0: prep (stats zero + bitmap) + weight transposes
    prep_k<<<1, 256, 0, stream>>>(label, sums, bm);
    {
        dim3 g1(DMLP / 32, DIMIN / 32);       // W1 [1536,512] -> W1t [512,1536]
        transpose_f16_tile_k<<<g1, 256, 0, stream>>>(W1, W1t, DIMIN, DMLP);
        dim3 g2(FDIM / 32, DMLP / 32);        // W2 [512,256] -> W2t [256,512]
        transpose_f16_tile_k<<<g2, 256, 0, stream>>>(W2, W2t, DMLP, FDIM);
    }

    // GEMM1: h = feat_in @ W1 + b1, conv + BN-stats fused
    // (64x128 tiles -> 256 XCD-clustered blocks; A read fp32 directly)
    gemm_f32a_t<128, false, true><<<256, 256, 0, stream>>>(
        feat_in, W1t, nullptr, nullptr, h, b1, DIMIN, DMLP, sums, sqs);

    // BN finish (scale/shift)
    bn_finish_k<<<2, 256, 0, stream>>>(sums, sqs, gamma, beta, bnsc, bnsh);

    // GEMM2: out2 = relu(h*sc+sh) @ W2 + b2, BN-apply fused in A-staging
    // (64x64 tiles -> 256 XCD-clustered blocks)
    gemm_f32a_t<64, true, false><<<256, 256, 0, stream>>>(
        h, W2t, bnsc, bnsh, out2, b2, DMLP, FDIM, nullptr, nullptr);

    // feat = l2norm(out2)
    l2norm_k<<<NROWS / 4, 256, 0, stream>>>(out2, feat, feath);

    // memory bank: per-label chains (bitmap-gated) + f16 materialization
    chain_k<<<NPAD / 4, 256, 0, stream>>>(label, feat, mp, bm, memh);

    // GEMM3: sim = feat @ mem^T   [4096, 10000]  (128x128 tiles -> 2528 blocks,
    // non-temporal C stores: don't let the 164 MB stream evict memh/feath)
    {
        dim3 g(NROWS / 128, NPAD / 128);
        gemm_t<128, 128, false, true><<<g, 256, 0, stream>>>(
            feath, memh, out, nullptr, FDIM, NCLS, NCLS, nullptr, nullptr);
    }
}

// Round 6
// 293.339 us; speedup vs baseline: 1.0453x; 1.0400x over previous
//
#include <hip/hip_runtime.h>
#include <stdint.h>

typedef _Float16 f16;
typedef _Float16 f16x4 __attribute__((ext_vector_type(4)));
typedef _Float16 f16x8 __attribute__((ext_vector_type(8)));
typedef float f32x4 __attribute__((ext_vector_type(4)));

typedef __attribute__((address_space(1))) void gvoid;
typedef __attribute__((address_space(3))) void lvoid;

#define NROWS 4096
#define DIMIN 1536
#define DMLP 512
#define FDIM 256
#define NCLS 10000
#define NPAD 10112   // 79 * 128
#define NBMW 320     // bitmap words (>= ceil(NCLS/32)=313)

__device__ __forceinline__ void load_lds16(const void* g, void* l) {
    // async global->LDS, 16B per lane; LDS dest = wave-uniform base + lane*16
    __builtin_amdgcn_global_load_lds((gvoid*)g, (lvoid*)l, 16, 0, 0);
}

// ---------------------------------------------------------------------------
// fp16 GEMM: C[M,N] = A[M,K] @ Bt[N,K]^T (+bias).
// Tile TM x TN per block (256 thr = 4 waves in 2x2), BK=64.
// 2-phase double-buffered pipeline: issue next K-tile's global_load_lds
// BEFORE computing the current tile, ONE __syncthreads per K-step.
// LDS per buffer: A then B, row-major [row][64k], XOR swizzle: 16B-group g
// of row r lives at slot g ^ (r & 7); staging permutes the GLOBAL source
// address, LDS dest stays linear (global_load_lds rule).
// STATS: fuse BatchNorm column sum/sumsq (atomicAdd) into the epilogue.
// NT: non-temporal C stores (streaming output, keep L2 for operands).
// SWAP: mfma(b,a) instead of mfma(a,b) -> lane holds 4 consecutive COLS of
//       one row -> dwordx4 C stores (4x fewer store instrs on the big
//       GEMM3 write stream). Same LDS reads, same fragments.
// ---------------------------------------------------------------------------
template<int TM, int TN, bool STATS, bool NT, bool SWAP>
__global__ __launch_bounds__(256) void gemm_t(
    const f16* __restrict__ A, const f16* __restrict__ Bt,
    float* __restrict__ C, const float* __restrict__ bias,
    int K, int ldc, int Nstore,
    float* __restrict__ sums, float* __restrict__ sqs)
{
    constexpr int BK = 64;
    constexpr int AM = TM / 32;
    constexpr int AN = TN / 32;
    constexpr int CA = TM * 8;
    constexpr int CB = TN * 8;
    constexpr int RTOT = (CA + CB) / 256;
    constexpr int SPAN = (TM + TN) * BK;
    static_assert(CA % 256 == 0, "A/B staging split must be round-aligned");
    static_assert(!(SWAP && STATS), "SWAP epilogue has no STATS path");

    __shared__ f16 smem[2 * SPAN];

    const int tid  = threadIdx.x;
    const int lane = tid & 63;
    const int w    = tid >> 6;
    const int wm   = (w >> 1) * (TM / 2);
    const int wn   = (w & 1) * (TN / 2);
    const int row0 = blockIdx.x * TM;
    const int col0 = blockIdx.y * TN;
    const int quad = lane >> 4;
    const int r16  = lane & 15;

    f32x4 acc[AM][AN] = {};

    const f16* gsrc[RTOT];
    int ldsoff[RTOT];
#pragma unroll
    for (int r = 0; r < RTOT; ++r) {
        int c = tid + r * 256;
        bool isA = (c < CA);
        int cc = isA ? c : c - CA;
        int row = cc >> 3;
        int gs = (cc & 7) ^ (row & 7);
        gsrc[r] = (isA ? A + (size_t)(row0 + row) * K
                       : Bt + (size_t)(col0 + row) * K) + gs * 8;
        ldsoff[r] = (isA ? 0 : TM * BK) + cc * 8;
    }

    const int nt = K / BK;

#pragma unroll
    for (int r = 0; r < RTOT; ++r)
        load_lds16(gsrc[r], smem + ldsoff[r]);
    __syncthreads();

    int buf = 0;
    for (int t = 0; t < nt; ++t) {
        if (t + 1 < nt) {
            const int k0 = (t + 1) * BK;
            const int o = (buf ^ 1) * SPAN;
#pragma unroll
            for (int r = 0; r < RTOT; ++r)
                load_lds16(gsrc[r] + k0, smem + o + ldsoff[r]);
        }
        const f16* As = smem + buf * SPAN;
        const f16* Bs = As + TM * BK;
#pragma unroll
        for (int ks = 0; ks < 2; ++ks) {
            f16x8 af[AM], bq[AN];
#pragma unroll
            for (int mi = 0; mi < AM; ++mi) {
                int row = wm + mi * 16 + r16;
                int slot = (ks * 4 + quad) ^ (r16 & 7);
                af[mi] = *(const f16x8*)&As[row * BK + slot * 8];
            }
#pragma unroll
            for (int ni = 0; ni < AN; ++ni) {
                int row = wn + ni * 16 + r16;
                int slot = (ks * 4 + quad) ^ (r16 & 7);
                bq[ni] = *(const f16x8*)&Bs[row * BK + slot * 8];
            }
#pragma unroll
            for (int mi = 0; mi < AM; ++mi)
#pragma unroll
                for (int ni = 0; ni < AN; ++ni) {
                    if constexpr (SWAP)
                        acc[mi][ni] = __builtin_amdgcn_mfma_f32_16x16x32_f16(
                            bq[ni], af[mi], acc[mi][ni], 0, 0, 0);
                    else
                        acc[mi][ni] = __builtin_amdgcn_mfma_f32_16x16x32_f16(
                            af[mi], bq[ni], acc[mi][ni], 0, 0, 0);
                }
        }
        __syncthreads();
        buf ^= 1;
    }

    if constexpr (SWAP) {
        // D = mfma(B,A): value = C[m][c], c = col0+wn+ni*16+quad*4+reg,
        // m = row0+wm+mi*16+r16 -> 4 consecutive cols per lane -> dwordx4
#pragma unroll
        for (int ni = 0; ni < AN; ++ni) {
            int c0 = col0 + wn + ni * 16 + quad * 4;
            if (c0 < Nstore) {      // Nstore%4==0 && c0%4==0 -> whole quad in
#pragma unroll
                for (int mi = 0; mi < AM; ++mi) {
                    int m = row0 + wm + mi * 16 + r16;
                    if constexpr (NT)
                        __builtin_nontemporal_store(acc[mi][ni],
                            (f32x4*)&C[(size_t)m * ldc + c0]);
                    else
                        *(f32x4*)&C[(size_t)m * ldc + c0] = acc[mi][ni];
                }
            }
        }
    } else {
        // C/D layout: col = lane&15, row = quad*4 + reg
#pragma unroll
        for (int ni = 0; ni < AN; ++ni) {
            int col = col0 + wn + ni * 16 + r16;
            float bv = bias ? bias[col] : 0.0f;
            float s = 0.0f, q = 0.0f;
            if (col < Nstore) {
#pragma unroll
                for (int mi = 0; mi < AM; ++mi) {
                    int rowb = row0 + wm + mi * 16 + quad * 4;
#pragma unroll
                    for (int r = 0; r < 4; ++r) {
                        float v = acc[mi][ni][r] + bv;
                        if constexpr (NT)
                            __builtin_nontemporal_store(v, &C[(size_t)(rowb + r) * ldc + col]);
                        else
                            C[(size_t)(rowb + r) * ldc + col] = v;
                        if constexpr (STATS) { s += v; q += v * v; }
                    }
                }
            }
            if constexpr (STATS) {
                s += __shfl_xor(s, 16); s += __shfl_xor(s, 32);
                q += __shfl_xor(q, 16); q += __shfl_xor(q, 32);
                if (quad == 0) {
                    atomicAdd(&sums[col], s);
                    atomicAdd(&sqs[col], q);
                }
            }
        }
    }
}

// ---------------------------------------------------------------------------
// merged setup: f32->f16 conv (blocks 0..6143), W1^T (6144..6911),
// W2^T (6912..7039), prep/bitmap (7040). One launch instead of four.
// Branch is uniform per block, so the in-branch __syncthreads is safe.
// ---------------------------------------------------------------------------
__device__ __forceinline__ void transpose_tile(
    const float* __restrict__ in, f16* __restrict__ out,
    int R, int C, int bxx, int byy, float* t, int tid)
{
    int tx = tid & 31, ty = tid >> 5;   // 32x8
    int c0 = bxx * 32, r0 = byy * 32;
#pragma unroll
    for (int k = 0; k < 4; ++k)
        t[(ty + k * 8) * 33 + tx] = in[(size_t)(r0 + ty + k * 8) * C + c0 + tx];
    __syncthreads();
#pragma unroll
    for (int k = 0; k < 4; ++k)
        out[(size_t)(c0 + ty + k * 8) * R + r0 + tx] = (f16)t[tx * 33 + ty + k * 8];
}

__global__ void setup_k(const float* __restrict__ feat_in, f16* __restrict__ A1h,
                        const float* __restrict__ W1, f16* __restrict__ W1t,
                        const float* __restrict__ W2, f16* __restrict__ W2t,
                        const int* __restrict__ label, float* __restrict__ stats,
                        unsigned int* __restrict__ bm)
{
    __shared__ float t[32 * 33];
    const int b = blockIdx.x, tid = threadIdx.x;
    if (b < 6144) {                               // conv: 4096*1536/4 elems
        int i = b * 256 + tid;
        float4 v = *(const float4*)&feat_in[(size_t)i * 4];
        f16x4 o = {(f16)v.x, (f16)v.y, (f16)v.z, (f16)v.w};
        *(f16x4*)&A1h[(size_t)i * 4] = o;
    } else if (b < 6912) {                        // W1 [1536,512] -> [512,1536]
        int idx = b - 6144;
        transpose_tile(W1, W1t, DIMIN, DMLP, idx & 15, idx >> 4, t, tid);
    } else if (b < 7040) {                        // W2 [512,256] -> [256,512]
        int idx = b - 6912;
        transpose_tile(W2, W2t, DMLP, FDIM, idx & 7, idx >> 3, t, tid);
    } else {                                      // prep: stats zero + bitmap
        unsigned int* lbm = (unsigned int*)t;
        for (int i = tid; i < NBMW; i += 256) lbm[i] = 0u;
        for (int i = tid; i < 2 * DMLP; i += 256) stats[i] = 0.0f;
        __syncthreads();
        for (int i = tid; i < NROWS; i += 256) {
            int y = label[i];
            atomicOr(&lbm[y >> 5], 1u << (y & 31));
        }
        __syncthreads();
        for (int i = tid; i < NBMW; i += 256) bm[i] = lbm[i];
    }
}

// ---------------------------------------------------------------------------
// BN apply + ReLU + cast to fp16; scale/shift recomputed inline from the
// raw sums/sumsq (deletes the bn_finish launch; identical fp32 ops).
__global__ void bn_apply_k(const float* __restrict__ h,
                           const float* __restrict__ sums, const float* __restrict__ sqs,
                           const float* __restrict__ gamma, const float* __restrict__ beta,
                           f16* __restrict__ out) {
    int i = blockIdx.x * 256 + threadIdx.x;     // over 4096*512/4
    int c = (i & 127) * 4;
    const float inv_n = 1.0f / 4096.0f;
    float4 s4 = *(const float4*)&sums[c];
    float4 q4 = *(const float4*)&sqs[c];
    float4 g4 = *(const float4*)&gamma[c];
    float4 b4 = *(const float4*)&beta[c];
    float4 sc, sh;
    {
        float mu = s4.x * inv_n, var = fmaxf(q4.x * inv_n - mu * mu, 0.0f);
        float a = rsqrtf(var + 1e-5f) * g4.x; sc.x = a; sh.x = b4.x - mu * a;
    }
    {
        float mu = s4.y * inv_n, var = fmaxf(q4.y * inv_n - mu * mu, 0.0f);
        float a = rsqrtf(var + 1e-5f) * g4.y; sc.y = a; sh.y = b4.y - mu * a;
    }
    {
        float mu = s4.z * inv_n, var = fmaxf(q4.z * inv_n - mu * mu, 0.0f);
        float a = rsqrtf(var + 1e-5f) * g4.z; sc.z = a; sh.z = b4.z - mu * a;
    }
    {
        float mu = s4.w * inv_n, var = fmaxf(q4.w * inv_n - mu * mu, 0.0f);
        float a = rsqrtf(var + 1e-5f) * g4.w; sc.w = a; sh.w = b4.w - mu * a;
    }
    float4 v = *(const float4*)&h[(size_t)i * 4];
    f16x4 o = {(f16)fmaxf(v.x * sc.x + sh.x, 0.0f),
               (f16)fmaxf(v.y * sc.y + sh.y, 0.0f),
               (f16)fmaxf(v.z * sc.z + sh.z, 0.0f),
               (f16)fmaxf(v.w * sc.w + sh.w, 0.0f)};
    *(f16x4*)&out[(size_t)i * 4] = o;
}

// row-wise L2 normalize out2[4096,256] -> feat fp32 + fp16; one wave/row
__global__ void l2norm_k(const float* __restrict__ X, float* __restrict__ Y, f16* __restrict__ Yh) {
    int wv = (blockIdx.x * 256 + threadIdx.x) >> 6;
    int lane = threadIdx.x & 63;
    float4 v = *(const float4*)&X[(size_t)wv * FDIM + lane * 4];
    float s = v.x * v.x + v.y * v.y + v.z * v.z + v.w * v.w;
#pragma unroll
    for (int off = 32; off > 0; off >>= 1) s += __shfl_xor(s, off);
    float inv = 1.0f / fmaxf(sqrtf(s), 1e-12f);
    float4 o = {v.x * inv, v.y * inv, v.z * inv, v.w * inv};
    *(float4*)&Y[(size_t)wv * FDIM + lane * 4] = o;
    f16x4 oh = {(f16)o.x, (f16)o.y, (f16)o.z, (f16)o.w};
    *(f16x4*)&Yh[(size_t)wv * FDIM + lane * 4] = oh;
}

// per-label sequential momentum chain + f16 memory-bank materialization.
// One wave per padded row; rows >= NCLS -> zeros; untouched rows (bitmap
// gate) skip the 64-iteration label scan entirely.
__global__ void chain_k(const int* __restrict__ label, const float* __restrict__ feat,
                        const float* __restrict__ mp, const unsigned int* __restrict__ bm,
                        f16* __restrict__ memh) {
    int y = (blockIdx.x * 256 + threadIdx.x) >> 6;
    int lane = threadIdx.x & 63;
    float4 m = {0.f, 0.f, 0.f, 0.f};
    if (y < NCLS) {
        m = *(const float4*)&mp[(size_t)y * FDIM + lane * 4];
        if ((bm[y >> 5] >> (y & 31)) & 1u) {
            for (int g = 0; g < 64; ++g) {
                int lab = label[g * 64 + lane];
                unsigned long long mask = __ballot(lab == y);
                while (mask) {
                    int b = __builtin_ctzll(mask);
                    mask &= mask - 1;
                    int i = g * 64 + b;
                    float4 x = *(const float4*)&feat[(size_t)i * FDIM + lane * 4];
                    m.x = 0.9f * m.x + 0.1f * x.x;
                    m.y = 0.9f * m.y + 0.1f * x.y;
                    m.z = 0.9f * m.z + 0.1f * x.z;
                    m.w = 0.9f * m.w + 0.1f * x.w;
                    float s = m.x * m.x + m.y * m.y + m.z * m.z + m.w * m.w;
#pragma unroll
                    for (int off = 32; off > 0; off >>= 1) s += __shfl_xor(s, off);
                    float inv = 1.0f / fmaxf(sqrtf(s), 1e-12f);
                    m.x *= inv; m.y *= inv; m.z *= inv; m.w *= inv;
                }
            }
        }
    }
    f16x4 o = {(f16)m.x, (f16)m.y, (f16)m.z, (f16)m.w};
    *(f16x4*)&memh[(size_t)y * FDIM + lane * 4] = o;
}

// ---------------------------------------------------------------------------
extern "C" void kernel_launch(void* const* d_in, const int* in_sizes, int n_in,
                              void* d_out, int out_size, void* d_ws, size_t ws_size,
                              hipStream_t stream) {
    const float* feat_in = (const float*)d_in[0];
    const int*   label   = (const int*)d_in[1];
    const float* W1      = (const float*)d_in[2];
    const float* b1      = (const float*)d_in[3];
    const float* gamma   = (const float*)d_in[4];
    const float* beta    = (const float*)d_in[5];
    const float* W2      = (const float*)d_in[6];
    const float* b2      = (const float*)d_in[7];
    const float* mp      = (const float*)d_in[8];
    float* out = (float*)d_out;

    char* w = (char*)d_ws;
    f16* A1h   = (f16*)w;   w += (size_t)NROWS * DIMIN * 2;   // 12.6 MB
    f16* W1t   = (f16*)w;   w += (size_t)DMLP * DIMIN * 2;    // 1.6 MB
    f16* W2t   = (f16*)w;   w += (size_t)FDIM * DMLP * 2;     // 0.26 MB
    float* h   = (float*)w; w += (size_t)NROWS * DMLP * 4;    // 8.4 MB
    f16* h2    = (f16*)w;   w += (size_t)NROWS * DMLP * 2;    // 4.2 MB
    float* out2= (float*)w; w += (size_t)NROWS * FDIM * 4;    // 4.2 MB
    float* feat= (float*)w; w += (size_t)NROWS * FDIM * 4;    // 4.2 MB
    f16* feath = (f16*)w;   w += (size_t)NROWS * FDIM * 2;    // 2.1 MB
    f16* memh  = (f16*)w;   w += (size_t)NPAD * FDIM * 2;     // 5.2 MB
    float* sums= (float*)w; w += DMLP * 4;                    // stats (contig)
    float* sqs = (float*)w; w += DMLP * 4;
    unsigned int* bm = (unsigned int*)w; w += NBMW * 4;       // touched bitmap

    // 1) merged setup: conv + W1^T + W2^T + prep (stats zero + bitmap)
    setup_k<<<7041, 256, 0, stream>>>(feat_in, A1h, W1, W1t, W2, W2t,
                                      label, sums, bm);

    // 2) GEMM1: h = feat_in16 @ W1 + b1, BN stats fused (128x64 -> 256 blocks)
    {
        dim3 g(NROWS / 128, DMLP / 64);
        gemm_t<128, 64, true, false, false><<<g, 256, 0, stream>>>(
            A1h, W1t, h, b1, DIMIN, DMLP, DMLP, sums, sqs);
    }

    // 3) BN apply (scale/shift recomputed inline) + ReLU + f16 cast
    bn_apply_k<<<(NROWS * DMLP / 4) / 256, 256, 0, stream>>>(
        h, sums, sqs, gamma, beta, h2);

    // 4) GEMM2: out2 = h2 @ W2 + b2   (64x64 tiles -> 256 blocks)
    {
        dim3 g(NROWS / 64, FDIM / 64);
        gemm_t<64, 64, false, false, false><<<g, 256, 0, stream>>>(
            h2, W2t, out2, b2, DMLP, FDIM, FDIM, nullptr, nullptr);
    }

    // 5) feat = l2norm(out2)
    l2norm_k<<<NROWS / 4, 256, 0, stream>>>(out2, feat, feath);

    // 6) memory bank: per-label chains (bitmap-gated) + f16 materialization
    chain_k<<<NPAD / 4, 256, 0, stream>>>(label, feat, mp, bm, memh);

    // 7) GEMM3: sim = feat @ mem^T  [4096, 10000] (128x128 -> 2528 blocks,
    //    swapped-operand epilogue -> dwordx4 NT stores on the 162 MB stream)
    {
        dim3 g(NROWS / 128, NPAD / 128);
        gemm_t<128, 128, false, true, true><<<g, 256, 0, stream>>>(
            feath, memh, out, nullptr, FDIM, NCLS, NCLS, nullptr, nullptr);
    }
}

// Round 7
// 291.915 us; speedup vs baseline: 1.0504x; 1.0049x over previous
//
#include <hip/hip_runtime.h>
#include <stdint.h>

typedef _Float16 f16;
typedef _Float16 f16x4 __attribute__((ext_vector_type(4)));
typedef _Float16 f16x8 __attribute__((ext_vector_type(8)));
typedef float f32x4 __attribute__((ext_vector_type(4)));

typedef __attribute__((address_space(1))) void gvoid;
typedef __attribute__((address_space(3))) void lvoid;

#define NROWS 4096
#define DIMIN 1536
#define DMLP 512
#define FDIM 256
#define NCLS 10000
#define NPAD 10112   // 79 * 128
#define NBMW 320     // bitmap words (>= ceil(NCLS/32)=313)

__device__ __forceinline__ void load_lds16(const void* g, void* l) {
    // async global->LDS, 16B per lane; LDS dest = wave-uniform base + lane*16
    __builtin_amdgcn_global_load_lds((gvoid*)g, (lvoid*)l, 16, 0, 0);
}

// ---------------------------------------------------------------------------
// fp16 GEMM: C[M,N] = A[M,K] @ Bt[N,K]^T (+bias).
// Tile TM x TN per block (256 thr = 4 waves in 2x2), BK=64.
// 2-phase double-buffered pipeline: issue next K-tile's global_load_lds
// BEFORE computing the current tile, ONE __syncthreads per K-step.
// LDS per buffer: A then B, row-major [row][64k], XOR swizzle: 16B-group g
// of row r lives at slot g ^ (r & 7); staging permutes the GLOBAL source
// address, LDS dest stays linear (global_load_lds rule).
// Grid is 1D NBX*NBY (must be %8==0), XCD-chunk-swizzled (T1, bijective):
// tile = (lin&7)*CHUNK + lin>>3; AMAJ picks which operand's panels stay
// local to an XCD's L2 (true: A row-panels; false: B col-panels).
// STATS: fuse BatchNorm column sum/sumsq (atomicAdd) into the epilogue.
// NT: non-temporal C stores. SWAP: mfma(b,a) -> lane holds 4 consecutive
// cols of one row -> dwordx4 C stores (GEMM3's 164 MB stream).
// ---------------------------------------------------------------------------
template<int TM, int TN, int NBX, int NBY, bool STATS, bool NT, bool SWAP, bool AMAJ>
__global__ __launch_bounds__(256) void gemm_t(
    const f16* __restrict__ A, const f16* __restrict__ Bt,
    float* __restrict__ C, const float* __restrict__ bias,
    int K, int ldc, int Nstore,
    float* __restrict__ sums, float* __restrict__ sqs)
{
    constexpr int BK = 64;
    constexpr int AM = TM / 32;
    constexpr int AN = TN / 32;
    constexpr int CA = TM * 8;
    constexpr int CB = TN * 8;
    constexpr int RTOT = (CA + CB) / 256;
    constexpr int SPAN = (TM + TN) * BK;
    constexpr int NTILES = NBX * NBY;
    constexpr int CHUNK = NTILES / 8;
    static_assert(CA % 256 == 0, "A/B staging split must be round-aligned");
    static_assert(NTILES % 8 == 0, "bijective XCD swizzle needs %8==0");
    static_assert(!(SWAP && STATS), "SWAP epilogue has no STATS path");

    __shared__ f16 smem[2 * SPAN];

    const int tid  = threadIdx.x;
    const int lane = tid & 63;
    const int w    = tid >> 6;
    const int wm   = (w >> 1) * (TM / 2);
    const int wn   = (w & 1) * (TN / 2);
    // XCD-chunked bijective swizzle (grid %8==0)
    const int lin  = blockIdx.x;
    const int tile = (lin & 7) * CHUNK + (lin >> 3);
    int bx, by;
    if constexpr (AMAJ) { bx = tile / NBY; by = tile % NBY; }   // A-panels L2-local
    else               { by = tile / NBX; bx = tile % NBX; }   // B-panels L2-local
    const int row0 = bx * TM;
    const int col0 = by * TN;
    const int quad = lane >> 4;
    const int r16  = lane & 15;

    f32x4 acc[AM][AN] = {};

    const f16* gsrc[RTOT];
    int ldsoff[RTOT];
#pragma unroll
    for (int r = 0; r < RTOT; ++r) {
        int c = tid + r * 256;
        bool isA = (c < CA);
        int cc = isA ? c : c - CA;
        int row = cc >> 3;
        int gs = (cc & 7) ^ (row & 7);
        gsrc[r] = (isA ? A + (size_t)(row0 + row) * K
                       : Bt + (size_t)(col0 + row) * K) + gs * 8;
        ldsoff[r] = (isA ? 0 : TM * BK) + cc * 8;
    }

    const int nt = K / BK;

#pragma unroll
    for (int r = 0; r < RTOT; ++r)
        load_lds16(gsrc[r], smem + ldsoff[r]);
    __syncthreads();

    int buf = 0;
    for (int t = 0; t < nt; ++t) {
        if (t + 1 < nt) {
            const int k0 = (t + 1) * BK;
            const int o = (buf ^ 1) * SPAN;
#pragma unroll
            for (int r = 0; r < RTOT; ++r)
                load_lds16(gsrc[r] + k0, smem + o + ldsoff[r]);
        }
        const f16* As = smem + buf * SPAN;
        const f16* Bs = As + TM * BK;
#pragma unroll
        for (int ks = 0; ks < 2; ++ks) {
            f16x8 af[AM], bq[AN];
#pragma unroll
            for (int mi = 0; mi < AM; ++mi) {
                int row = wm + mi * 16 + r16;
                int slot = (ks * 4 + quad) ^ (r16 & 7);
                af[mi] = *(const f16x8*)&As[row * BK + slot * 8];
            }
#pragma unroll
            for (int ni = 0; ni < AN; ++ni) {
                int row = wn + ni * 16 + r16;
                int slot = (ks * 4 + quad) ^ (r16 & 7);
                bq[ni] = *(const f16x8*)&Bs[row * BK + slot * 8];
            }
#pragma unroll
            for (int mi = 0; mi < AM; ++mi)
#pragma unroll
                for (int ni = 0; ni < AN; ++ni) {
                    if constexpr (SWAP)
                        acc[mi][ni] = __builtin_amdgcn_mfma_f32_16x16x32_f16(
                            bq[ni], af[mi], acc[mi][ni], 0, 0, 0);
                    else
                        acc[mi][ni] = __builtin_amdgcn_mfma_f32_16x16x32_f16(
                            af[mi], bq[ni], acc[mi][ni], 0, 0, 0);
                }
        }
        __syncthreads();
        buf ^= 1;
    }

    if constexpr (SWAP) {
        // D = mfma(B,A): value = C[m][c], c = col0+wn+ni*16+quad*4+reg,
        // m = row0+wm+mi*16+r16 -> 4 consecutive cols per lane -> dwordx4
#pragma unroll
        for (int ni = 0; ni < AN; ++ni) {
            int c0 = col0 + wn + ni * 16 + quad * 4;
            if (c0 < Nstore) {      // Nstore%4==0 && c0%4==0 -> whole quad in
#pragma unroll
                for (int mi = 0; mi < AM; ++mi) {
                    int m = row0 + wm + mi * 16 + r16;
                    if constexpr (NT)
                        __builtin_nontemporal_store(acc[mi][ni],
                            (f32x4*)&C[(size_t)m * ldc + c0]);
                    else
                        *(f32x4*)&C[(size_t)m * ldc + c0] = acc[mi][ni];
                }
            }
        }
    } else {
        // C/D layout: col = lane&15, row = quad*4 + reg
#pragma unroll
        for (int ni = 0; ni < AN; ++ni) {
            int col = col0 + wn + ni * 16 + r16;
            float bv = bias ? bias[col] : 0.0f;
            float s = 0.0f, q = 0.0f;
            if (col < Nstore) {
#pragma unroll
                for (int mi = 0; mi < AM; ++mi) {
                    int rowb = row0 + wm + mi * 16 + quad * 4;
#pragma unroll
                    for (int r = 0; r < 4; ++r) {
                        float v = acc[mi][ni][r] + bv;
                        if constexpr (NT)
                            __builtin_nontemporal_store(v, &C[(size_t)(rowb + r) * ldc + col]);
                        else
                            C[(size_t)(rowb + r) * ldc + col] = v;
                        if constexpr (STATS) { s += v; q += v * v; }
                    }
                }
            }
            if constexpr (STATS) {
                s += __shfl_xor(s, 16); s += __shfl_xor(s, 32);
                q += __shfl_xor(q, 16); q += __shfl_xor(q, 32);
                if (quad == 0) {
                    atomicAdd(&sums[col], s);
                    atomicAdd(&sqs[col], q);
                }
            }
        }
    }
}

// ---------------------------------------------------------------------------
// merged setup: f32->f16 conv (blocks 0..6143), W1^T (6144..6911),
// W2^T (6912..7039), prep/bitmap (7040). One launch instead of four.
// Branch is uniform per block, so the in-branch __syncthreads is safe.
// ---------------------------------------------------------------------------
__device__ __forceinline__ void transpose_tile(
    const float* __restrict__ in, f16* __restrict__ out,
    int R, int C, int bxx, int byy, float* t, int tid)
{
    int tx = tid & 31, ty = tid >> 5;   // 32x8
    int c0 = bxx * 32, r0 = byy * 32;
#pragma unroll
    for (int k = 0; k < 4; ++k)
        t[(ty + k * 8) * 33 + tx] = in[(size_t)(r0 + ty + k * 8) * C + c0 + tx];
    __syncthreads();
#pragma unroll
    for (int k = 0; k < 4; ++k)
        out[(size_t)(c0 + ty + k * 8) * R + r0 + tx] = (f16)t[tx * 33 + ty + k * 8];
}

__global__ void setup_k(const float* __restrict__ feat_in, f16* __restrict__ A1h,
                        const float* __restrict__ W1, f16* __restrict__ W1t,
                        const float* __restrict__ W2, f16* __restrict__ W2t,
                        const int* __restrict__ label, float* __restrict__ stats,
                        unsigned int* __restrict__ bm)
{
    __shared__ float t[32 * 33];
    const int b = blockIdx.x, tid = threadIdx.x;
    if (b < 6144) {                               // conv: 4096*1536/4 elems
        int i = b * 256 + tid;
        float4 v = *(const float4*)&feat_in[(size_t)i * 4];
        f16x4 o = {(f16)v.x, (f16)v.y, (f16)v.z, (f16)v.w};
        *(f16x4*)&A1h[(size_t)i * 4] = o;
    } else if (b < 6912) {                        // W1 [1536,512] -> [512,1536]
        int idx = b - 6144;
        transpose_tile(W1, W1t, DIMIN, DMLP, idx & 15, idx >> 4, t, tid);
    } else if (b < 7040) {                        // W2 [512,256] -> [256,512]
        int idx = b - 6912;
        transpose_tile(W2, W2t, DMLP, FDIM, idx & 7, idx >> 3, t, tid);
    } else {                                      // prep: stats zero + bitmap
        unsigned int* lbm = (unsigned int*)t;
        for (int i = tid; i < NBMW; i += 256) lbm[i] = 0u;
        for (int i = tid; i < 2 * DMLP; i += 256) stats[i] = 0.0f;
        __syncthreads();
        for (int i = tid; i < NROWS; i += 256) {
            int y = label[i];
            atomicOr(&lbm[y >> 5], 1u << (y & 31));
        }
        __syncthreads();
        for (int i = tid; i < NBMW; i += 256) bm[i] = lbm[i];
    }
}

// ---------------------------------------------------------------------------
// BN apply + ReLU + cast to fp16; scale/shift recomputed inline from the
// raw sums/sumsq (no bn_finish launch; identical fp32 ops).
__global__ void bn_apply_k(const float* __restrict__ h,
                           const float* __restrict__ sums, const float* __restrict__ sqs,
                           const float* __restrict__ gamma, const float* __restrict__ beta,
                           f16* __restrict__ out) {
    int i = blockIdx.x * 256 + threadIdx.x;     // over 4096*512/4
    int c = (i & 127) * 4;
    const float inv_n = 1.0f / 4096.0f;
    float4 s4 = *(const float4*)&sums[c];
    float4 q4 = *(const float4*)&sqs[c];
    float4 g4 = *(const float4*)&gamma[c];
    float4 b4 = *(const float4*)&beta[c];
    float4 sc, sh;
    {
        float mu = s4.x * inv_n, var = fmaxf(q4.x * inv_n - mu * mu, 0.0f);
        float a = rsqrtf(var + 1e-5f) * g4.x; sc.x = a; sh.x = b4.x - mu * a;
    }
    {
        float mu = s4.y * inv_n, var = fmaxf(q4.y * inv_n - mu * mu, 0.0f);
        float a = rsqrtf(var + 1e-5f) * g4.y; sc.y = a; sh.y = b4.y - mu * a;
    }
    {
        float mu = s4.z * inv_n, var = fmaxf(q4.z * inv_n - mu * mu, 0.0f);
        float a = rsqrtf(var + 1e-5f) * g4.z; sc.z = a; sh.z = b4.z - mu * a;
    }
    {
        float mu = s4.w * inv_n, var = fmaxf(q4.w * inv_n - mu * mu, 0.0f);
        float a = rsqrtf(var + 1e-5f) * g4.w; sc.w = a; sh.w = b4.w - mu * a;
    }
    float4 v = *(const float4*)&h[(size_t)i * 4];
    f16x4 o = {(f16)fmaxf(v.x * sc.x + sh.x, 0.0f),
               (f16)fmaxf(v.y * sc.y + sh.y, 0.0f),
               (f16)fmaxf(v.z * sc.z + sh.z, 0.0f),
               (f16)fmaxf(v.w * sc.w + sh.w, 0.0f)};
    *(f16x4*)&out[(size_t)i * 4] = o;
}

// row-wise L2 normalize out2[4096,256] -> feath fp16 only (fp32 feat buffer
// deleted; chain consumes the f16 copy). One wave/row.
__global__ void l2norm_k(const float* __restrict__ X, f16* __restrict__ Yh) {
    int wv = (blockIdx.x * 256 + threadIdx.x) >> 6;
    int lane = threadIdx.x & 63;
    float4 v = *(const float4*)&X[(size_t)wv * FDIM + lane * 4];
    float s = v.x * v.x + v.y * v.y + v.z * v.z + v.w * v.w;
#pragma unroll
    for (int off = 32; off > 0; off >>= 1) s += __shfl_xor(s, off);
    float inv = 1.0f / fmaxf(sqrtf(s), 1e-12f);
    f16x4 oh = {(f16)(v.x * inv), (f16)(v.y * inv),
                (f16)(v.z * inv), (f16)(v.w * inv)};
    *(f16x4*)&Yh[(size_t)wv * FDIM + lane * 4] = oh;
}

// per-label sequential momentum chain + f16 memory-bank materialization.
// One wave per padded row; rows >= NCLS -> zeros; untouched rows (bitmap
// gate) skip the 64-iteration label scan entirely. feat read as f16.
__global__ void chain_k(const int* __restrict__ label, const f16* __restrict__ feath,
                        const float* __restrict__ mp, const unsigned int* __restrict__ bm,
                        f16* __restrict__ memh) {
    int y = (blockIdx.x * 256 + threadIdx.x) >> 6;
    int lane = threadIdx.x & 63;
    float4 m = {0.f, 0.f, 0.f, 0.f};
    if (y < NCLS) {
        m = *(const float4*)&mp[(size_t)y * FDIM + lane * 4];
        if ((bm[y >> 5] >> (y & 31)) & 1u) {
            for (int g = 0; g < 64; ++g) {
                int lab = label[g * 64 + lane];
                unsigned long long mask = __ballot(lab == y);
                while (mask) {
                    int b = __builtin_ctzll(mask);
                    mask &= mask - 1;
                    int i = g * 64 + b;
                    f16x4 xr = *(const f16x4*)&feath[(size_t)i * FDIM + lane * 4];
                    m.x = 0.9f * m.x + 0.1f * (float)xr[0];
                    m.y = 0.9f * m.y + 0.1f * (float)xr[1];
                    m.z = 0.9f * m.z + 0.1f * (float)xr[2];
                    m.w = 0.9f * m.w + 0.1f * (float)xr[3];
                    float s = m.x * m.x + m.y * m.y + m.z * m.z + m.w * m.w;
#pragma unroll
                    for (int off = 32; off > 0; off >>= 1) s += __shfl_xor(s, off);
                    float inv = 1.0f / fmaxf(sqrtf(s), 1e-12f);
                    m.x *= inv; m.y *= inv; m.z *= inv; m.w *= inv;
                }
            }
        }
    }
    f16x4 o = {(f16)m.x, (f16)m.y, (f16)m.z, (f16)m.w};
    *(f16x4*)&memh[(size_t)y * FDIM + lane * 4] = o;
}

// ---------------------------------------------------------------------------
extern "C" void kernel_launch(void* const* d_in, const int* in_sizes, int n_in,
                              void* d_out, int out_size, void* d_ws, size_t ws_size,
                              hipStream_t stream) {
    const float* feat_in = (const float*)d_in[0];
    const int*   label   = (const int*)d_in[1];
    const float* W1      = (const float*)d_in[2];
    const float* b1      = (const float*)d_in[3];
    const float* gamma   = (const float*)d_in[4];
    const float* beta    = (const float*)d_in[5];
    const float* W2      = (const float*)d_in[6];
    const float* b2      = (const float*)d_in[7];
    const float* mp      = (const float*)d_in[8];
    float* out = (float*)d_out;

    char* w = (char*)d_ws;
    f16* A1h   = (f16*)w;   w += (size_t)NROWS * DIMIN * 2;   // 12.6 MB
    f16* W1t   = (f16*)w;   w += (size_t)DMLP * DIMIN * 2;    // 1.6 MB
    f16* W2t   = (f16*)w;   w += (size_t)FDIM * DMLP * 2;     // 0.26 MB
    float* h   = (float*)w; w += (size_t)NROWS * DMLP * 4;    // 8.4 MB
    f16* h2    = (f16*)w;   w += (size_t)NROWS * DMLP * 2;    // 4.2 MB
    float* out2= (float*)w; w += (size_t)NROWS * FDIM * 4;    // 4.2 MB
    f16* feath = (f16*)w;   w += (size_t)NROWS * FDIM * 2;    // 2.1 MB
    f16* memh  = (f16*)w;   w += (size_t)NPAD * FDIM * 2;     // 5.2 MB
    float* sums= (float*)w; w += DMLP * 4;                    // stats (contig)
    float* sqs = (float*)w; w += DMLP * 4;
    unsigned int* bm = (unsigned int*)w; w += NBMW * 4;       // touched bitmap

    // 1) merged setup: conv + W1^T + W2^T + prep (stats zero + bitmap)
    setup_k<<<7041, 256, 0, stream>>>(feat_in, A1h, W1, W1t, W2, W2t,
                                      label, sums, bm);

    // 2) GEMM1: h = feat_in16 @ W1 + b1, BN stats fused
    //    (128x64 tiles, 32x8 grid, XCD-swizzled A-major -> A slice L2-local)
    gemm_t<128, 64, 32, 8, true, false, false, true><<<256, 256, 0, stream>>>(
        A1h, W1t, h, b1, DIMIN, DMLP, DMLP, sums, sqs);

    // 3) BN apply (scale/shift recomputed inline) + ReLU + f16 cast
    bn_apply_k<<<(NROWS * DMLP / 4) / 256, 256, 0, stream>>>(
        h, sums, sqs, gamma, beta, h2);

    // 4) GEMM2: out2 = h2 @ W2 + b2 (64x64 tiles, 64x4 grid, A-major swizzle)
    gemm_t<64, 64, 64, 4, false, false, false, true><<<256, 256, 0, stream>>>(
        h2, W2t, out2, b2, DMLP, FDIM, FDIM, nullptr, nullptr);

    // 5) feath = f16(l2norm(out2))
    l2norm_k<<<NROWS / 4, 256, 0, stream>>>(out2, feath);

    // 6) memory bank: per-label chains (bitmap-gated, f16 feat reads)
    chain_k<<<NPAD / 4, 256, 0, stream>>>(label, feath, mp, bm, memh);

    // 7) GEMM3: sim = feat @ mem^T  [4096, 10000] (128x128, 32x79 grid,
    //    B-major swizzle -> each XCD owns ~10 memh panels, L2-resident;
    //    swapped-operand epilogue -> dwordx4 NT stores on the 164 MB stream)
    gemm_t<128, 128, 32, 79, false, true, true, false><<<2528, 256, 0, stream>>>(
        feath, memh, out, nullptr, FDIM, NCLS, NCLS, nullptr, nullptr);
}

// Round 8
// 288.347 us; speedup vs baseline: 1.0634x; 1.0124x over previous
//
#include <hip/hip_runtime.h>
#include <stdint.h>

typedef _Float16 f16;
typedef _Float16 f16x4 __attribute__((ext_vector_type(4)));
typedef _Float16 f16x8 __attribute__((ext_vector_type(8)));
typedef float f32x4 __attribute__((ext_vector_type(4)));

typedef __attribute__((address_space(1))) void gvoid;
typedef __attribute__((address_space(3))) void lvoid;

#define NROWS 4096
#define DIMIN 1536
#define DMLP 512
#define FDIM 256
#define NCLS 10000
#define NPAD 10112   // 79 * 128
#define MAXD 32      // per-class list capacity (fallback scan if exceeded)

__device__ __forceinline__ void load_lds16(const void* g, void* l) {
    // async global->LDS, 16B per lane; LDS dest = wave-uniform base + lane*16
    __builtin_amdgcn_global_load_lds((gvoid*)g, (lvoid*)l, 16, 0, 0);
}

// ---------------------------------------------------------------------------
// fp16 GEMM: C[M,N] = A[M,K] @ Bt[N,K]^T (+bias).
// Tile TM x TN per block (256 thr = 4 waves in 2x2), BK=64.
// 2-phase double-buffered pipeline: issue next K-tile's global_load_lds
// BEFORE computing the current tile, ONE __syncthreads per K-step.
// LDS per buffer: A then B, row-major [row][64k], XOR swizzle: 16B-group g
// of row r lives at slot g ^ (r & 7); staging permutes the GLOBAL source
// address, LDS dest stays linear (global_load_lds rule).
// Grid is 1D NBX*NBY (must be %8==0), XCD-chunk-swizzled (T1, bijective):
// tile = (lin&7)*CHUNK + lin>>3; AMAJ picks which operand's panels stay
// local to an XCD's L2 (true: A row-panels; false: B col-panels).
// STATS: fuse BatchNorm column sum/sumsq (atomicAdd) into the epilogue.
// NT: non-temporal C stores. SWAP: mfma(b,a) -> lane holds 4 consecutive
// cols of one row -> dwordx4 C stores (GEMM3's 164 MB stream).
// ---------------------------------------------------------------------------
template<int TM, int TN, int NBX, int NBY, bool STATS, bool NT, bool SWAP, bool AMAJ>
__global__ __launch_bounds__(256) void gemm_t(
    const f16* __restrict__ A, const f16* __restrict__ Bt,
    float* __restrict__ C, const float* __restrict__ bias,
    int K, int ldc, int Nstore,
    float* __restrict__ sums, float* __restrict__ sqs)
{
    constexpr int BK = 64;
    constexpr int AM = TM / 32;
    constexpr int AN = TN / 32;
    constexpr int CA = TM * 8;
    constexpr int CB = TN * 8;
    constexpr int RTOT = (CA + CB) / 256;
    constexpr int SPAN = (TM + TN) * BK;
    constexpr int NTILES = NBX * NBY;
    constexpr int CHUNK = NTILES / 8;
    static_assert(CA % 256 == 0, "A/B staging split must be round-aligned");
    static_assert(NTILES % 8 == 0, "bijective XCD swizzle needs %8==0");
    static_assert(!(SWAP && STATS), "SWAP epilogue has no STATS path");

    __shared__ f16 smem[2 * SPAN];

    const int tid  = threadIdx.x;
    const int lane = tid & 63;
    const int w    = tid >> 6;
    const int wm   = (w >> 1) * (TM / 2);
    const int wn   = (w & 1) * (TN / 2);
    // XCD-chunked bijective swizzle (grid %8==0)
    const int lin  = blockIdx.x;
    const int tile = (lin & 7) * CHUNK + (lin >> 3);
    int bx, by;
    if constexpr (AMAJ) { bx = tile / NBY; by = tile % NBY; }   // A-panels L2-local
    else               { by = tile / NBX; bx = tile % NBX; }   // B-panels L2-local
    const int row0 = bx * TM;
    const int col0 = by * TN;
    const int quad = lane >> 4;
    const int r16  = lane & 15;

    f32x4 acc[AM][AN] = {};

    const f16* gsrc[RTOT];
    int ldsoff[RTOT];
#pragma unroll
    for (int r = 0; r < RTOT; ++r) {
        int c = tid + r * 256;
        bool isA = (c < CA);
        int cc = isA ? c : c - CA;
        int row = cc >> 3;
        int gs = (cc & 7) ^ (row & 7);
        gsrc[r] = (isA ? A + (size_t)(row0 + row) * K
                       : Bt + (size_t)(col0 + row) * K) + gs * 8;
        ldsoff[r] = (isA ? 0 : TM * BK) + cc * 8;
    }

    const int nt = K / BK;

#pragma unroll
    for (int r = 0; r < RTOT; ++r)
        load_lds16(gsrc[r], smem + ldsoff[r]);
    __syncthreads();

    int buf = 0;
    for (int t = 0; t < nt; ++t) {
        if (t + 1 < nt) {
            const int k0 = (t + 1) * BK;
            const int o = (buf ^ 1) * SPAN;
#pragma unroll
            for (int r = 0; r < RTOT; ++r)
                load_lds16(gsrc[r] + k0, smem + o + ldsoff[r]);
        }
        const f16* As = smem + buf * SPAN;
        const f16* Bs = As + TM * BK;
#pragma unroll
        for (int ks = 0; ks < 2; ++ks) {
            f16x8 af[AM], bq[AN];
#pragma unroll
            for (int mi = 0; mi < AM; ++mi) {
                int row = wm + mi * 16 + r16;
                int slot = (ks * 4 + quad) ^ (r16 & 7);
                af[mi] = *(const f16x8*)&As[row * BK + slot * 8];
            }
#pragma unroll
            for (int ni = 0; ni < AN; ++ni) {
                int row = wn + ni * 16 + r16;
                int slot = (ks * 4 + quad) ^ (r16 & 7);
                bq[ni] = *(const f16x8*)&Bs[row * BK + slot * 8];
            }
#pragma unroll
            for (int mi = 0; mi < AM; ++mi)
#pragma unroll
                for (int ni = 0; ni < AN; ++ni) {
                    if constexpr (SWAP)
                        acc[mi][ni] = __builtin_amdgcn_mfma_f32_16x16x32_f16(
                            bq[ni], af[mi], acc[mi][ni], 0, 0, 0);
                    else
                        acc[mi][ni] = __builtin_amdgcn_mfma_f32_16x16x32_f16(
                            af[mi], bq[ni], acc[mi][ni], 0, 0, 0);
                }
        }
        __syncthreads();
        buf ^= 1;
    }

    if constexpr (SWAP) {
        // D = mfma(B,A): value = C[m][c], c = col0+wn+ni*16+quad*4+reg,
        // m = row0+wm+mi*16+r16 -> 4 consecutive cols per lane -> dwordx4
#pragma unroll
        for (int ni = 0; ni < AN; ++ni) {
            int c0 = col0 + wn + ni * 16 + quad * 4;
            if (c0 < Nstore) {      // Nstore%4==0 && c0%4==0 -> whole quad in
#pragma unroll
                for (int mi = 0; mi < AM; ++mi) {
                    int m = row0 + wm + mi * 16 + r16;
                    if constexpr (NT)
                        __builtin_nontemporal_store(acc[mi][ni],
                            (f32x4*)&C[(size_t)m * ldc + c0]);
                    else
                        *(f32x4*)&C[(size_t)m * ldc + c0] = acc[mi][ni];
                }
            }
        }
    } else {
        // C/D layout: col = lane&15, row = quad*4 + reg
#pragma unroll
        for (int ni = 0; ni < AN; ++ni) {
            int col = col0 + wn + ni * 16 + r16;
            float bv = bias ? bias[col] : 0.0f;
            float s = 0.0f, q = 0.0f;
            if (col < Nstore) {
#pragma unroll
                for (int mi = 0; mi < AM; ++mi) {
                    int rowb = row0 + wm + mi * 16 + quad * 4;
#pragma unroll
                    for (int r = 0; r < 4; ++r) {
                        float v = acc[mi][ni][r] + bv;
                        if constexpr (NT)
                            __builtin_nontemporal_store(v, &C[(size_t)(rowb + r) * ldc + col]);
                        else
                            C[(size_t)(rowb + r) * ldc + col] = v;
                        if constexpr (STATS) { s += v; q += v * v; }
                    }
                }
            }
            if constexpr (STATS) {
                s += __shfl_xor(s, 16); s += __shfl_xor(s, 32);
                q += __shfl_xor(q, 16); q += __shfl_xor(q, 32);
                if (quad == 0) {
                    atomicAdd(&sums[col], s);
                    atomicAdd(&sqs[col], q);
                }
            }
        }
    }
}

// ---------------------------------------------------------------------------
// merged setup: f32->f16 conv (blocks 0..6143), W1^T (6144..6911),
// W2^T (6912..7039), prep (7040): zero BN stats + build per-class CSR
// lists (counts + up-to-MAXD sample indices; order re-derived in chain_k).
// Branch is uniform per block, so the in-branch __syncthreads is safe.
// ---------------------------------------------------------------------------
__device__ __forceinline__ void transpose_tile(
    const float* __restrict__ in, f16* __restrict__ out,
    int R, int C, int bxx, int byy, float* t, int tid)
{
    int tx = tid & 31, ty = tid >> 5;   // 32x8
    int c0 = bxx * 32, r0 = byy * 32;
#pragma unroll
    for (int k = 0; k < 4; ++k)
        t[(ty + k * 8) * 33 + tx] = in[(size_t)(r0 + ty + k * 8) * C + c0 + tx];
    __syncthreads();
#pragma unroll
    for (int k = 0; k < 4; ++k)
        out[(size_t)(c0 + ty + k * 8) * R + r0 + tx] = (f16)t[tx * 33 + ty + k * 8];
}

__global__ void setup_k(const float* __restrict__ feat_in, f16* __restrict__ A1h,
                        const float* __restrict__ W1, f16* __restrict__ W1t,
                        const float* __restrict__ W2, f16* __restrict__ W2t,
                        const int* __restrict__ label, float* __restrict__ stats,
                        int* __restrict__ counts, int* __restrict__ lists)
{
    __shared__ float t[32 * 33];
    const int b = blockIdx.x, tid = threadIdx.x;
    if (b < 6144) {                               // conv: 4096*1536/4 elems
        int i = b * 256 + tid;
        float4 v = *(const float4*)&feat_in[(size_t)i * 4];
        f16x4 o = {(f16)v.x, (f16)v.y, (f16)v.z, (f16)v.w};
        *(f16x4*)&A1h[(size_t)i * 4] = o;
    } else if (b < 6912) {                        // W1 [1536,512] -> [512,1536]
        int idx = b - 6144;
        transpose_tile(W1, W1t, DIMIN, DMLP, idx & 15, idx >> 4, t, tid);
    } else if (b < 7040) {                        // W2 [512,256] -> [256,512]
        int idx = b - 6912;
        transpose_tile(W2, W2t, DMLP, FDIM, idx & 7, idx >> 3, t, tid);
    } else {                                      // prep: stats zero + CSR build
        for (int i = tid; i < 2 * DMLP; i += 256) stats[i] = 0.0f;
        for (int i = tid; i < NPAD; i += 256) counts[i] = 0;
        __syncthreads();                          // block-wide global visibility
        for (int i = tid; i < NROWS; i += 256) {
            int y = label[i];
            int pos = atomicAdd(&counts[y], 1);
            if (pos < MAXD) lists[y * MAXD + pos] = i;
        }
    }
}

// ---------------------------------------------------------------------------
// BN apply + ReLU + cast to fp16; scale/shift recomputed inline from the
// raw sums/sumsq (no bn_finish launch; identical fp32 ops).
__global__ void bn_apply_k(const float* __restrict__ h,
                           const float* __restrict__ sums, const float* __restrict__ sqs,
                           const float* __restrict__ gamma, const float* __restrict__ beta,
                           f16* __restrict__ out) {
    int i = blockIdx.x * 256 + threadIdx.x;     // over 4096*512/4
    int c = (i & 127) * 4;
    const float inv_n = 1.0f / 4096.0f;
    float4 s4 = *(const float4*)&sums[c];
    float4 q4 = *(const float4*)&sqs[c];
    float4 g4 = *(const float4*)&gamma[c];
    float4 b4 = *(const float4*)&beta[c];
    float4 sc, sh;
    {
        float mu = s4.x * inv_n, var = fmaxf(q4.x * inv_n - mu * mu, 0.0f);
        float a = rsqrtf(var + 1e-5f) * g4.x; sc.x = a; sh.x = b4.x - mu * a;
    }
    {
        float mu = s4.y * inv_n, var = fmaxf(q4.y * inv_n - mu * mu, 0.0f);
        float a = rsqrtf(var + 1e-5f) * g4.y; sc.y = a; sh.y = b4.y - mu * a;
    }
    {
        float mu = s4.z * inv_n, var = fmaxf(q4.z * inv_n - mu * mu, 0.0f);
        float a = rsqrtf(var + 1e-5f) * g4.z; sc.z = a; sh.z = b4.z - mu * a;
    }
    {
        float mu = s4.w * inv_n, var = fmaxf(q4.w * inv_n - mu * mu, 0.0f);
        float a = rsqrtf(var + 1e-5f) * g4.w; sc.w = a; sh.w = b4.w - mu * a;
    }
    float4 v = *(const float4*)&h[(size_t)i * 4];
    f16x4 o = {(f16)fmaxf(v.x * sc.x + sh.x, 0.0f),
               (f16)fmaxf(v.y * sc.y + sh.y, 0.0f),
               (f16)fmaxf(v.z * sc.z + sh.z, 0.0f),
               (f16)fmaxf(v.w * sc.w + sh.w, 0.0f)};
    *(f16x4*)&out[(size_t)i * 4] = o;
}

// row-wise L2 normalize out2[4096,256] -> feath fp16; one wave/row
__global__ void l2norm_k(const float* __restrict__ X, f16* __restrict__ Yh) {
    int wv = (blockIdx.x * 256 + threadIdx.x) >> 6;
    int lane = threadIdx.x & 63;
    float4 v = *(const float4*)&X[(size_t)wv * FDIM + lane * 4];
    float s = v.x * v.x + v.y * v.y + v.z * v.z + v.w * v.w;
#pragma unroll
    for (int off = 32; off > 0; off >>= 1) s += __shfl_xor(s, off);
    float inv = 1.0f / fmaxf(sqrtf(s), 1e-12f);
    f16x4 oh = {(f16)(v.x * inv), (f16)(v.y * inv),
                (f16)(v.z * inv), (f16)(v.w * inv)};
    *(f16x4*)&Yh[(size_t)wv * FDIM + lane * 4] = oh;
}

// per-label sequential momentum chain + f16 memory-bank materialization.
// One wave per padded row; rows >= NCLS -> zeros. CSR fast path: process
// this class's samples directly in ascending-index order (selection on the
// fly from the unordered list; c is typically 1-3). Ballot-scan fallback
// only if a class has > MAXD samples (correctness guard).
__global__ void chain_k(const int* __restrict__ label, const f16* __restrict__ feath,
                        const float* __restrict__ mp, const int* __restrict__ counts,
                        const int* __restrict__ lists, f16* __restrict__ memh) {
    int y = (blockIdx.x * 256 + threadIdx.x) >> 6;
    int lane = threadIdx.x & 63;
    float4 m = {0.f, 0.f, 0.f, 0.f};
    if (y < NCLS) {
        m = *(const float4*)&mp[(size_t)y * FDIM + lane * 4];
        int c = counts[y];
        if (c > 0 && c <= MAXD) {
            int last = -1;
            for (int j = 0; j < c; ++j) {
                int best = 0x7fffffff;
                for (int t2 = 0; t2 < c; ++t2) {
                    int ii = lists[y * MAXD + t2];     // L1-resident after j=0
                    if (ii > last && ii < best) best = ii;
                }
                last = best;
                f16x4 xr = *(const f16x4*)&feath[(size_t)best * FDIM + lane * 4];
                m.x = 0.9f * m.x + 0.1f * (float)xr[0];
                m.y = 0.9f * m.y + 0.1f * (float)xr[1];
                m.z = 0.9f * m.z + 0.1f * (float)xr[2];
                m.w = 0.9f * m.w + 0.1f * (float)xr[3];
                float s = m.x * m.x + m.y * m.y + m.z * m.z + m.w * m.w;
#pragma unroll
                for (int off = 32; off > 0; off >>= 1) s += __shfl_xor(s, off);
                float inv = 1.0f / fmaxf(sqrtf(s), 1e-12f);
                m.x *= inv; m.y *= inv; m.z *= inv; m.w *= inv;
            }
        } else if (c > MAXD) {                        // fallback: full scan
            for (int g = 0; g < 64; ++g) {
                int lab = label[g * 64 + lane];
                unsigned long long mask = __ballot(lab == y);
                while (mask) {
                    int b = __builtin_ctzll(mask);
                    mask &= mask - 1;
                    int i = g * 64 + b;
                    f16x4 xr = *(const f16x4*)&feath[(size_t)i * FDIM + lane * 4];
                    m.x = 0.9f * m.x + 0.1f * (float)xr[0];
                    m.y = 0.9f * m.y + 0.1f * (float)xr[1];
                    m.z = 0.9f * m.z + 0.1f * (float)xr[2];
                    m.w = 0.9f * m.w + 0.1f * (float)xr[3];
                    float s = m.x * m.x + m.y * m.y + m.z * m.z + m.w * m.w;
#pragma unroll
                    for (int off = 32; off > 0; off >>= 1) s += __shfl_xor(s, off);
                    float inv = 1.0f / fmaxf(sqrtf(s), 1e-12f);
                    m.x *= inv; m.y *= inv; m.z *= inv; m.w *= inv;
                }
            }
        }
    }
    f16x4 o = {(f16)m.x, (f16)m.y, (f16)m.z, (f16)m.w};
    *(f16x4*)&memh[(size_t)y * FDIM + lane * 4] = o;
}

// ---------------------------------------------------------------------------
extern "C" void kernel_launch(void* const* d_in, const int* in_sizes, int n_in,
                              void* d_out, int out_size, void* d_ws, size_t ws_size,
                              hipStream_t stream) {
    const float* feat_in = (const float*)d_in[0];
    const int*   label   = (const int*)d_in[1];
    const float* W1      = (const float*)d_in[2];
    const float* b1      = (const float*)d_in[3];
    const float* gamma   = (const float*)d_in[4];
    const float* beta    = (const float*)d_in[5];
    const float* W2      = (const float*)d_in[6];
    const float* b2      = (const float*)d_in[7];
    const float* mp      = (const float*)d_in[8];
    float* out = (float*)d_out;

    char* w = (char*)d_ws;
    f16* A1h   = (f16*)w;   w += (size_t)NROWS * DIMIN * 2;   // 12.6 MB
    f16* W1t   = (f16*)w;   w += (size_t)DMLP * DIMIN * 2;    // 1.6 MB
    f16* W2t   = (f16*)w;   w += (size_t)FDIM * DMLP * 2;     // 0.26 MB
    float* h   = (float*)w; w += (size_t)NROWS * DMLP * 4;    // 8.4 MB
    f16* h2    = (f16*)w;   w += (size_t)NROWS * DMLP * 2;    // 4.2 MB
    float* out2= (float*)w; w += (size_t)NROWS * FDIM * 4;    // 4.2 MB
    f16* feath = (f16*)w;   w += (size_t)NROWS * FDIM * 2;    // 2.1 MB
    f16* memh  = (f16*)w;   w += (size_t)NPAD * FDIM * 2;     // 5.2 MB
    float* sums= (float*)w; w += DMLP * 4;                    // stats (contig)
    float* sqs = (float*)w; w += DMLP * 4;
    int* counts= (int*)w;   w += (size_t)NPAD * 4;            // CSR counts
    int* lists = (int*)w;   w += (size_t)NCLS * MAXD * 4;     // CSR lists 1.28MB

    // 1) merged setup: conv + W1^T + W2^T + prep (stats zero + CSR build)
    setup_k<<<7041, 256, 0, stream>>>(feat_in, A1h, W1, W1t, W2, W2t,
                                      label, sums, counts, lists);

    // 2) GEMM1: h = feat_in16 @ W1 + b1, BN stats fused
    //    (128x64 tiles, 32x8 grid, XCD-swizzled A-major -> A slice L2-local)
    gemm_t<128, 64, 32, 8, true, false, false, true><<<256, 256, 0, stream>>>(
        A1h, W1t, h, b1, DIMIN, DMLP, DMLP, sums, sqs);

    // 3) BN apply (scale/shift recomputed inline) + ReLU + f16 cast
    bn_apply_k<<<(NROWS * DMLP / 4) / 256, 256, 0, stream>>>(
        h, sums, sqs, gamma, beta, h2);

    // 4) GEMM2: out2 = h2 @ W2 + b2 (64x64 tiles, 64x4 grid, A-major swizzle)
    gemm_t<64, 64, 64, 4, false, false, false, true><<<256, 256, 0, stream>>>(
        h2, W2t, out2, b2, DMLP, FDIM, FDIM, nullptr, nullptr);

    // 5) feath = f16(l2norm(out2))
    l2norm_k<<<NROWS / 4, 256, 0, stream>>>(out2, feath);

    // 6) memory bank: per-label chains via CSR lists (scan fallback >MAXD)
    chain_k<<<NPAD / 4, 256, 0, stream>>>(label, feath, mp, counts, lists, memh);

    // 7) GEMM3: sim = feat @ mem^T  [4096, 10000] (128x128, 32x79 grid,
    //    B-major swizzle -> each XCD owns ~10 memh panels, L2-resident;
    //    swapped-operand epilogue -> dwordx4 NT stores on the 164 MB stream)
    gemm_t<128, 128, 32, 79, false, true, true, false><<<2528, 256, 0, stream>>>(
        feath, memh, out, nullptr, FDIM, NCLS, NCLS, nullptr, nullptr);
}

// Round 9
// 285.195 us; speedup vs baseline: 1.0751x; 1.0111x over previous
//
#include <hip/hip_runtime.h>
#include <stdint.h>

typedef _Float16 f16;
typedef _Float16 f16x4 __attribute__((ext_vector_type(4)));
typedef _Float16 f16x8 __attribute__((ext_vector_type(8)));
typedef float f32x4 __attribute__((ext_vector_type(4)));

typedef __attribute__((address_space(1))) void gvoid;
typedef __attribute__((address_space(3))) void lvoid;

#define NROWS 4096
#define DIMIN 1536
#define DMLP 512
#define FDIM 256
#define NCLS 10000
#define NPAD 10112   // 79 * 128
#define MAXD 32      // per-class list capacity (fallback scan if exceeded)

__device__ __forceinline__ void load_lds16(const void* g, void* l) {
    // async global->LDS, 16B per lane; LDS dest = wave-uniform base + lane*16
    __builtin_amdgcn_global_load_lds((gvoid*)g, (lvoid*)l, 16, 0, 0);
}

// ---------------------------------------------------------------------------
// fp16 GEMM: C[M,N] = A[M,K] @ Bt[N,K]^T (+bias).
// Tile TM x TN per block (256 thr = 4 waves in 2x2), BK=64.
// 2-phase double-buffered pipeline: issue next K-tile's global_load_lds
// BEFORE computing the current tile, ONE __syncthreads per K-step.
// LDS per buffer: A then B, row-major [row][64k], XOR swizzle: 16B-group g
// of row r lives at slot g ^ (r & 7); staging permutes the GLOBAL source
// address, LDS dest stays linear (global_load_lds rule).
// Grid is 1D NBX*NBY (must be %8==0), XCD-chunk-swizzled (T1, bijective):
// tile = (lin&7)*CHUNK + lin>>3; AMAJ picks which operand's panels stay
// local to an XCD's L2 (true: A row-panels; false: B col-panels).
// STATS: fuse BatchNorm column sum/sumsq (atomicAdd) into the epilogue
//        (stats computed from the fp32 accumulator BEFORE any f16 cast).
// NT: non-temporal C stores. SWAP: mfma(b,a) -> lane holds 4 consecutive
// cols of one row -> dwordx4 C stores (GEMM3's 164 MB stream).
// F16OUT: cast the epilogue store to f16 (halves intermediate traffic).
// ---------------------------------------------------------------------------
template<int TM, int TN, int NBX, int NBY,
         bool STATS, bool NT, bool SWAP, bool AMAJ, bool F16OUT>
__global__ __launch_bounds__(256) void gemm_t(
    const f16* __restrict__ A, const f16* __restrict__ Bt,
    void* __restrict__ Cv, const float* __restrict__ bias,
    int K, int ldc, int Nstore,
    float* __restrict__ sums, float* __restrict__ sqs)
{
    constexpr int BK = 64;
    constexpr int AM = TM / 32;
    constexpr int AN = TN / 32;
    constexpr int CA = TM * 8;
    constexpr int CB = TN * 8;
    constexpr int RTOT = (CA + CB) / 256;
    constexpr int SPAN = (TM + TN) * BK;
    constexpr int NTILES = NBX * NBY;
    constexpr int CHUNK = NTILES / 8;
    static_assert(CA % 256 == 0, "A/B staging split must be round-aligned");
    static_assert(NTILES % 8 == 0, "bijective XCD swizzle needs %8==0");
    static_assert(!(SWAP && STATS), "SWAP epilogue has no STATS path");
    static_assert(!(SWAP && F16OUT), "SWAP epilogue is fp32-only");

    __shared__ f16 smem[2 * SPAN];

    const int tid  = threadIdx.x;
    const int lane = tid & 63;
    const int w    = tid >> 6;
    const int wm   = (w >> 1) * (TM / 2);
    const int wn   = (w & 1) * (TN / 2);
    // XCD-chunked bijective swizzle (grid %8==0)
    const int lin  = blockIdx.x;
    const int tile = (lin & 7) * CHUNK + (lin >> 3);
    int bx, by;
    if constexpr (AMAJ) { bx = tile / NBY; by = tile % NBY; }   // A-panels L2-local
    else               { by = tile / NBX; bx = tile % NBX; }   // B-panels L2-local
    const int row0 = bx * TM;
    const int col0 = by * TN;
    const int quad = lane >> 4;
    const int r16  = lane & 15;

    f32x4 acc[AM][AN] = {};

    const f16* gsrc[RTOT];
    int ldsoff[RTOT];
#pragma unroll
    for (int r = 0; r < RTOT; ++r) {
        int c = tid + r * 256;
        bool isA = (c < CA);
        int cc = isA ? c : c - CA;
        int row = cc >> 3;
        int gs = (cc & 7) ^ (row & 7);
        gsrc[r] = (isA ? A + (size_t)(row0 + row) * K
                       : Bt + (size_t)(col0 + row) * K) + gs * 8;
        ldsoff[r] = (isA ? 0 : TM * BK) + cc * 8;
    }

    const int nt = K / BK;

#pragma unroll
    for (int r = 0; r < RTOT; ++r)
        load_lds16(gsrc[r], smem + ldsoff[r]);
    __syncthreads();

    int buf = 0;
    for (int t = 0; t < nt; ++t) {
        if (t + 1 < nt) {
            const int k0 = (t + 1) * BK;
            const int o = (buf ^ 1) * SPAN;
#pragma unroll
            for (int r = 0; r < RTOT; ++r)
                load_lds16(gsrc[r] + k0, smem + o + ldsoff[r]);
        }
        const f16* As = smem + buf * SPAN;
        const f16* Bs = As + TM * BK;
#pragma unroll
        for (int ks = 0; ks < 2; ++ks) {
            f16x8 af[AM], bq[AN];
#pragma unroll
            for (int mi = 0; mi < AM; ++mi) {
                int row = wm + mi * 16 + r16;
                int slot = (ks * 4 + quad) ^ (r16 & 7);
                af[mi] = *(const f16x8*)&As[row * BK + slot * 8];
            }
#pragma unroll
            for (int ni = 0; ni < AN; ++ni) {
                int row = wn + ni * 16 + r16;
                int slot = (ks * 4 + quad) ^ (r16 & 7);
                bq[ni] = *(const f16x8*)&Bs[row * BK + slot * 8];
            }
#pragma unroll
            for (int mi = 0; mi < AM; ++mi)
#pragma unroll
                for (int ni = 0; ni < AN; ++ni) {
                    if constexpr (SWAP)
                        acc[mi][ni] = __builtin_amdgcn_mfma_f32_16x16x32_f16(
                            bq[ni], af[mi], acc[mi][ni], 0, 0, 0);
                    else
                        acc[mi][ni] = __builtin_amdgcn_mfma_f32_16x16x32_f16(
                            af[mi], bq[ni], acc[mi][ni], 0, 0, 0);
                }
        }
        __syncthreads();
        buf ^= 1;
    }

    if constexpr (SWAP) {
        float* C = (float*)Cv;
        // D = mfma(B,A): value = C[m][c], c = col0+wn+ni*16+quad*4+reg,
        // m = row0+wm+mi*16+r16 -> 4 consecutive cols per lane -> dwordx4
#pragma unroll
        for (int ni = 0; ni < AN; ++ni) {
            int c0 = col0 + wn + ni * 16 + quad * 4;
            if (c0 < Nstore) {      // Nstore%4==0 && c0%4==0 -> whole quad in
#pragma unroll
                for (int mi = 0; mi < AM; ++mi) {
                    int m = row0 + wm + mi * 16 + r16;
                    if constexpr (NT)
                        __builtin_nontemporal_store(acc[mi][ni],
                            (f32x4*)&C[(size_t)m * ldc + c0]);
                    else
                        *(f32x4*)&C[(size_t)m * ldc + c0] = acc[mi][ni];
                }
            }
        }
    } else {
        // C/D layout: col = lane&15, row = quad*4 + reg
#pragma unroll
        for (int ni = 0; ni < AN; ++ni) {
            int col = col0 + wn + ni * 16 + r16;
            float bv = bias ? bias[col] : 0.0f;
            float s = 0.0f, q = 0.0f;
            if (col < Nstore) {
#pragma unroll
                for (int mi = 0; mi < AM; ++mi) {
                    int rowb = row0 + wm + mi * 16 + quad * 4;
#pragma unroll
                    for (int r = 0; r < 4; ++r) {
                        float v = acc[mi][ni][r] + bv;
                        if constexpr (F16OUT)
                            ((f16*)Cv)[(size_t)(rowb + r) * ldc + col] = (f16)v;
                        else if constexpr (NT)
                            __builtin_nontemporal_store(v, &((float*)Cv)[(size_t)(rowb + r) * ldc + col]);
                        else
                            ((float*)Cv)[(size_t)(rowb + r) * ldc + col] = v;
                        if constexpr (STATS) { s += v; q += v * v; }
                    }
                }
            }
            if constexpr (STATS) {
                s += __shfl_xor(s, 16); s += __shfl_xor(s, 32);
                q += __shfl_xor(q, 16); q += __shfl_xor(q, 32);
                if (quad == 0) {
                    atomicAdd(&sums[col], s);
                    atomicAdd(&sqs[col], q);
                }
            }
        }
    }
}

// ---------------------------------------------------------------------------
// merged setup: f32->f16 conv (blocks 0..6143), W1^T (6144..6911),
// W2^T (6912..7039), prep (7040): zero BN stats + build per-class CSR
// lists (counts + up-to-MAXD sample indices; order re-derived in chain_k).
// Branch is uniform per block, so the in-branch __syncthreads is safe.
// ---------------------------------------------------------------------------
__device__ __forceinline__ void transpose_tile(
    const float* __restrict__ in, f16* __restrict__ out,
    int R, int C, int bxx, int byy, float* t, int tid)
{
    int tx = tid & 31, ty = tid >> 5;   // 32x8
    int c0 = bxx * 32, r0 = byy * 32;
#pragma unroll
    for (int k = 0; k < 4; ++k)
        t[(ty + k * 8) * 33 + tx] = in[(size_t)(r0 + ty + k * 8) * C + c0 + tx];
    __syncthreads();
#pragma unroll
    for (int k = 0; k < 4; ++k)
        out[(size_t)(c0 + ty + k * 8) * R + r0 + tx] = (f16)t[tx * 33 + ty + k * 8];
}

__global__ void setup_k(const float* __restrict__ feat_in, f16* __restrict__ A1h,
                        const float* __restrict__ W1, f16* __restrict__ W1t,
                        const float* __restrict__ W2, f16* __restrict__ W2t,
                        const int* __restrict__ label, float* __restrict__ stats,
                        int* __restrict__ counts, int* __restrict__ lists)
{
    __shared__ float t[32 * 33];
    const int b = blockIdx.x, tid = threadIdx.x;
    if (b < 6144) {                               // conv: 4096*1536/4 elems
        int i = b * 256 + tid;
        float4 v = *(const float4*)&feat_in[(size_t)i * 4];
        f16x4 o = {(f16)v.x, (f16)v.y, (f16)v.z, (f16)v.w};
        *(f16x4*)&A1h[(size_t)i * 4] = o;
    } else if (b < 6912) {                        // W1 [1536,512] -> [512,1536]
        int idx = b - 6144;
        transpose_tile(W1, W1t, DIMIN, DMLP, idx & 15, idx >> 4, t, tid);
    } else if (b < 7040) {                        // W2 [512,256] -> [256,512]
        int idx = b - 6912;
        transpose_tile(W2, W2t, DMLP, FDIM, idx & 7, idx >> 3, t, tid);
    } else {                                      // prep: stats zero + CSR build
        for (int i = tid; i < 2 * DMLP; i += 256) stats[i] = 0.0f;
        for (int i = tid; i < NPAD; i += 256) counts[i] = 0;
        __syncthreads();                          // block-wide global visibility
        for (int i = tid; i < NROWS; i += 256) {
            int y = label[i];
            int pos = atomicAdd(&counts[y], 1);
            if (pos < MAXD) lists[y * MAXD + pos] = i;
        }
    }
}

// ---------------------------------------------------------------------------
// BN apply + ReLU; h stored f16 (stats were computed from fp32 in GEMM1's
// epilogue, so mean/var are exact). scale/shift recomputed inline.
__global__ void bn_apply_k(const f16* __restrict__ h16,
                           const float* __restrict__ sums, const float* __restrict__ sqs,
                           const float* __restrict__ gamma, const float* __restrict__ beta,
                           f16* __restrict__ out) {
    int i = blockIdx.x * 256 + threadIdx.x;     // over 4096*512/4
    int c = (i & 127) * 4;
    const float inv_n = 1.0f / 4096.0f;
    float4 s4 = *(const float4*)&sums[c];
    float4 q4 = *(const float4*)&sqs[c];
    float4 g4 = *(const float4*)&gamma[c];
    float4 b4 = *(const float4*)&beta[c];
    float4 sc, sh;
    {
        float mu = s4.x * inv_n, var = fmaxf(q4.x * inv_n - mu * mu, 0.0f);
        float a = rsqrtf(var + 1e-5f) * g4.x; sc.x = a; sh.x = b4.x - mu * a;
    }
    {
        float mu = s4.y * inv_n, var = fmaxf(q4.y * inv_n - mu * mu, 0.0f);
        float a = rsqrtf(var + 1e-5f) * g4.y; sc.y = a; sh.y = b4.y - mu * a;
    }
    {
        float mu = s4.z * inv_n, var = fmaxf(q4.z * inv_n - mu * mu, 0.0f);
        float a = rsqrtf(var + 1e-5f) * g4.z; sc.z = a; sh.z = b4.z - mu * a;
    }
    {
        float mu = s4.w * inv_n, var = fmaxf(q4.w * inv_n - mu * mu, 0.0f);
        float a = rsqrtf(var + 1e-5f) * g4.w; sc.w = a; sh.w = b4.w - mu * a;
    }
    f16x4 hv = *(const f16x4*)&h16[(size_t)i * 4];
    f16x4 o = {(f16)fmaxf((float)hv[0] * sc.x + sh.x, 0.0f),
               (f16)fmaxf((float)hv[1] * sc.y + sh.y, 0.0f),
               (f16)fmaxf((float)hv[2] * sc.z + sh.z, 0.0f),
               (f16)fmaxf((float)hv[3] * sc.w + sh.w, 0.0f)};
    *(f16x4*)&out[(size_t)i * 4] = o;
}

// row-wise L2 normalize out2h[4096,256] (f16) -> feath fp16; one wave/row
__global__ void l2norm_k(const f16* __restrict__ Xh, f16* __restrict__ Yh) {
    int wv = (blockIdx.x * 256 + threadIdx.x) >> 6;
    int lane = threadIdx.x & 63;
    f16x4 xv = *(const f16x4*)&Xh[(size_t)wv * FDIM + lane * 4];
    float4 v = {(float)xv[0], (float)xv[1], (float)xv[2], (float)xv[3]};
    float s = v.x * v.x + v.y * v.y + v.z * v.z + v.w * v.w;
#pragma unroll
    for (int off = 32; off > 0; off >>= 1) s += __shfl_xor(s, off);
    float inv = 1.0f / fmaxf(sqrtf(s), 1e-12f);
    f16x4 oh = {(f16)(v.x * inv), (f16)(v.y * inv),
                (f16)(v.z * inv), (f16)(v.w * inv)};
    *(f16x4*)&Yh[(size_t)wv * FDIM + lane * 4] = oh;
}

// per-label sequential momentum chain + f16 memory-bank materialization.
// One wave per padded row; rows >= NCLS -> zeros. CSR fast path: process
// this class's samples directly in ascending-index order (selection on the
// fly from the unordered list; c is typically 1-3). Ballot-scan fallback
// only if a class has > MAXD samples (correctness guard).
__global__ void chain_k(const int* __restrict__ label, const f16* __restrict__ feath,
                        const float* __restrict__ mp, const int* __restrict__ counts,
                        const int* __restrict__ lists, f16* __restrict__ memh) {
    int y = (blockIdx.x * 256 + threadIdx.x) >> 6;
    int lane = threadIdx.x & 63;
    float4 m = {0.f, 0.f, 0.f, 0.f};
    if (y < NCLS) {
        m = *(const float4*)&mp[(size_t)y * FDIM + lane * 4];
        int c = counts[y];
        if (c > 0 && c <= MAXD) {
            int last = -1;
            for (int j = 0; j < c; ++j) {
                int best = 0x7fffffff;
                for (int t2 = 0; t2 < c; ++t2) {
                    int ii = lists[y * MAXD + t2];     // L1-resident after j=0
                    if (ii > last && ii < best) best = ii;
                }
                last = best;
                f16x4 xr = *(const f16x4*)&feath[(size_t)best * FDIM + lane * 4];
                m.x = 0.9f * m.x + 0.1f * (float)xr[0];
                m.y = 0.9f * m.y + 0.1f * (float)xr[1];
                m.z = 0.9f * m.z + 0.1f * (float)xr[2];
                m.w = 0.9f * m.w + 0.1f * (float)xr[3];
                float s = m.x * m.x + m.y * m.y + m.z * m.z + m.w * m.w;
#pragma unroll
                for (int off = 32; off > 0; off >>= 1) s += __shfl_xor(s, off);
                float inv = 1.0f / fmaxf(sqrtf(s), 1e-12f);
                m.x *= inv; m.y *= inv; m.z *= inv; m.w *= inv;
            }
        } else if (c > MAXD) {                        // fallback: full scan
            for (int g = 0; g < 64; ++g) {
                int lab = label[g * 64 + lane];
                unsigned long long mask = __ballot(lab == y);
                while (mask) {
                    int b = __builtin_ctzll(mask);
                    mask &= mask - 1;
                    int i = g * 64 + b;
                    f16x4 xr = *(const f16x4*)&feath[(size_t)i * FDIM + lane * 4];
                    m.x = 0.9f * m.x + 0.1f * (float)xr[0];
                    m.y = 0.9f * m.y + 0.1f * (float)xr[1];
                    m.z = 0.9f * m.z + 0.1f * (float)xr[2];
                    m.w = 0.9f * m.w + 0.1f * (float)xr[3];
                    float s = m.x * m.x + m.y * m.y + m.z * m.z + m.w * m.w;
#pragma unroll
                    for (int off = 32; off > 0; off >>= 1) s += __shfl_xor(s, off);
                    float inv = 1.0f / fmaxf(sqrtf(s), 1e-12f);
                    m.x *= inv; m.y *= inv; m.z *= inv; m.w *= inv;
                }
            }
        }
    }
    f16x4 o = {(f16)m.x, (f16)m.y, (f16)m.z, (f16)m.w};
    *(f16x4*)&memh[(size_t)y * FDIM + lane * 4] = o;
}

// ---------------------------------------------------------------------------
extern "C" void kernel_launch(void* const* d_in, const int* in_sizes, int n_in,
                              void* d_out, int out_size, void* d_ws, size_t ws_size,
                              hipStream_t stream) {
    const float* feat_in = (const float*)d_in[0];
    const int*   label   = (const int*)d_in[1];
    const float* W1      = (const float*)d_in[2];
    const float* b1      = (const float*)d_in[3];
    const float* gamma   = (const float*)d_in[4];
    const float* beta    = (const float*)d_in[5];
    const float* W2      = (const float*)d_in[6];
    const float* b2      = (const float*)d_in[7];
    const float* mp      = (const float*)d_in[8];
    float* out = (float*)d_out;

    char* w = (char*)d_ws;
    f16* A1h   = (f16*)w;   w += (size_t)NROWS * DIMIN * 2;   // 12.6 MB
    f16* W1t   = (f16*)w;   w += (size_t)DMLP * DIMIN * 2;    // 1.6 MB
    f16* W2t   = (f16*)w;   w += (size_t)FDIM * DMLP * 2;     // 0.26 MB
    f16* h16   = (f16*)w;   w += (size_t)NROWS * DMLP * 2;    // 4.2 MB (f16 now)
    f16* h2    = (f16*)w;   w += (size_t)NROWS * DMLP * 2;    // 4.2 MB
    f16* out2h = (f16*)w;   w += (size_t)NROWS * FDIM * 2;    // 2.1 MB (f16 now)
    f16* feath = (f16*)w;   w += (size_t)NROWS * FDIM * 2;    // 2.1 MB
    f16* memh  = (f16*)w;   w += (size_t)NPAD * FDIM * 2;     // 5.2 MB
    float* sums= (float*)w; w += DMLP * 4;                    // stats (contig)
    float* sqs = (float*)w; w += DMLP * 4;
    int* counts= (int*)w;   w += (size_t)NPAD * 4;            // CSR counts
    int* lists = (int*)w;   w += (size_t)NCLS * MAXD * 4;     // CSR lists 1.28MB

    // 1) merged setup: conv + W1^T + W2^T + prep (stats zero + CSR build)
    setup_k<<<7041, 256, 0, stream>>>(feat_in, A1h, W1, W1t, W2, W2t,
                                      label, sums, counts, lists);

    // 2) GEMM1: h16 = f16(feat_in16 @ W1 + b1), BN stats fused (exact fp32)
    //    (128x64 tiles, 32x8 grid, XCD-swizzled A-major -> A slice L2-local)
    gemm_t<128, 64, 32, 8, true, false, false, true, true>
        <<<256, 256, 0, stream>>>(
        A1h, W1t, h16, b1, DIMIN, DMLP, DMLP, sums, sqs);

    // 3) BN apply (scale/shift recomputed inline) + ReLU (f16 in/out)
    bn_apply_k<<<(NROWS * DMLP / 4) / 256, 256, 0, stream>>>(
        h16, sums, sqs, gamma, beta, h2);

    // 4) GEMM2: out2h = f16(h2 @ W2 + b2) (64x64, 64x4 grid, A-major swizzle)
    gemm_t<64, 64, 64, 4, false, false, false, true, true>
        <<<256, 256, 0, stream>>>(
        h2, W2t, out2h, b2, DMLP, FDIM, FDIM, nullptr, nullptr);

    // 5) feath = f16(l2norm(out2h))
    l2norm_k<<<NROWS / 4, 256, 0, stream>>>(out2h, feath);

    // 6) memory bank: per-label chains via CSR lists (scan fallback >MAXD)
    chain_k<<<NPAD / 4, 256, 0, stream>>>(label, feath, mp, counts, lists, memh);

    // 7) GEMM3: sim = feat @ mem^T  [4096, 10000] (128x128, 32x79 grid,
    //    B-major swizzle -> each XCD owns ~10 memh panels, L2-resident;
    //    swapped-operand epilogue -> dwordx4 NT stores on the 164 MB stream)
    gemm_t<128, 128, 32, 79, false, true, true, false, false>
        <<<2528, 256, 0, stream>>>(
        feath, memh, out, nullptr, FDIM, NCLS, NCLS, nullptr, nullptr);
}